// Round 5
// baseline (41895.914 us; speedup 1.0000x reference)
//
#include <hip/hip_runtime.h>
#include <stdint.h>
#include <stddef.h>

// LSTMQNetwork: B=64, T=4096, D=128, H=512, A=18
//
// Persistent-RNN, flag-free "data-as-flag" design:
//  - 128 recurrence blocks: 8 groups x 16 CUs; CU owns 32 h-cols.
//    Wh/Wi stationary in VGPRs as bf16 MFMA B-frags.
//  - h published per step into a t-indexed ring (R slots) as h' = h + s*1.5,
//    s = +/-1 by ring generation parity. |h|<1 strictly => sign of every
//    stored bf16 == generation parity => consumers detect freshness from the
//    data's own sign bits; the detecting poll already carries the payload.
//  - bias corrected analytically: h'@W = h@W + 1.5*s*colsum(W), folded into
//    the gate bias (two precomputed variants).
//  - producers: fire-and-forget u64 agent-scope atomic stores; NO fences, NO
//    flags, NO __syncthreads in the loop. obs double-buffered in registers.
//  - 8 worker blocks (4 waves, steps mod 4) compute qs = h@Wv behind the
//    producers; back-pressure via qdone counters every R/4 steps.
//  - FIX (R4): lstm_fill stamps the ENTIRE ring with 0x8000 (-0.0 = stale
//    for gen 0) before slot 0 is seeded (zero-filled ws looks gen0-fresh).
//  - FIX (R5): consumer u64 row stride was n*64 (=256 shorts) instead of
//    n*128 (=512 shorts) -> lanes read row n/2 interleaved; deterministic
//    corruption (R3/R4 absmax 1.0117 identical). Corrected in both polls.

#define B_   64
#define T_   4096
#define D_   128
#define H_   512
#define G4_  2048
#define A_   18
#define QOFF (2 * B_ * H_)
#define BIAS 1.5f

typedef float f32x4  __attribute__((ext_vector_type(4)));
typedef short bf16x8 __attribute__((ext_vector_type(8)));
#define MFMA __builtin_amdgcn_mfma_f32_16x16x32_bf16

#define QD_IDX(g,w)  (((g)*4 + (w)) * 16)   // one counter per 64B line
#define CTL_DWORDS   1024
#define HS_OFF       65536                   // byte offset of h ring in ws

__device__ __forceinline__ short f2bf(float x) {
    union { float f; uint32_t u; } v; v.f = x;
    uint32_t r = (v.u + 0x7fffu + ((v.u >> 16) & 1u)) >> 16;  // RNE
    return (short)(uint16_t)r;
}
__device__ __forceinline__ float bf2f(short s) {
    union { uint32_t u; float f; } v; v.u = ((uint32_t)(uint16_t)s) << 16;
    return v.f;
}
__device__ __forceinline__ float sigm(float x) {
    return __builtin_amdgcn_rcpf(1.0f + __builtin_amdgcn_exp2f(-1.4426950408889634f * x));
}
__device__ __forceinline__ float tanh_(float x) {
    return 2.0f * __builtin_amdgcn_rcpf(1.0f + __builtin_amdgcn_exp2f(-2.8853900817779268f * x)) - 1.0f;
}

// stamp ctl=0 and the whole ring stale (0x8000 = -0.0, sign bit set)
__global__ void lstm_fill(unsigned* __restrict__ ctl, uint4* __restrict__ hs4,
                          int nchunks) {
    int idx = blockIdx.x * blockDim.x + threadIdx.x;
    int nt  = gridDim.x * blockDim.x;
    for (int i = idx; i < CTL_DWORDS; i += nt) ctl[i] = 0u;
    const uint4 v = {0x80008000u, 0x80008000u, 0x80008000u, 0x80008000u};
    for (int i = idx; i < nchunks; i += nt) hs4[i] = v;
}

// seed slot 0 with h_0 + 1.5 (generation 0 => positive sign)
__global__ void lstm_init0(const float* __restrict__ init_h,
                           short* __restrict__ hs, int R) {
    int idx = blockIdx.x * blockDim.x + threadIdx.x;
    int nt  = gridDim.x * blockDim.x;
    for (int e = idx; e < B_ * H_; e += nt) {
        int row = e >> 9, col = e & 511;
        int g = row >> 3, r8 = row & 7;
        hs[(size_t)g * R * 4096 + (size_t)r8 * 512 + col] = f2bf(init_h[e] + BIAS);
    }
}

__global__ void __launch_bounds__(256, 1) lstm_main(
    const float* __restrict__ obses, const float* __restrict__ init_c,
    const float* __restrict__ Wi,    const float* __restrict__ Wh,
    const float* __restrict__ bvec,  const float* __restrict__ Wv,
    const float* __restrict__ bv,    float* __restrict__ out,
    unsigned* ctl, short* hs, int R, int lg2R)
{
    const int bid = blockIdx.x;
    const int w   = threadIdx.x >> 6;
    const int l   = threadIdx.x & 63;
    const int n   = l & 15;
    const int kg  = l >> 4;
    const int Rm  = R - 1;

    if (bid < 128) {
        // ---------------- recurrence producer ----------------
        const int g = bid & 7;
        const int k = bid >> 3;            // 0..15
        short* hsg = hs + (size_t)g * R * 4096;

        const int colb = k * 32 + w * 8 + (n & 3);
        const int gate = n >> 2;

        bf16x8 whF[2][16]; bf16x8 wiF[2][4];
        float  whsum[2] = {0.f, 0.f}; float bregv[2];
#pragma unroll
        for (int c = 0; c < 2; ++c) {
            const int gcol = gate * 512 + colb + c * 4;
#pragma unroll
            for (int ch = 0; ch < 16; ++ch) {
                bf16x8 v;
#pragma unroll
                for (int j = 0; j < 8; ++j) {
                    short sbf = f2bf(Wh[(size_t)(ch * 32 + kg * 8 + j) * G4_ + gcol]);
                    v[j] = sbf; whsum[c] += bf2f(sbf);
                }
                whF[c][ch] = v;
            }
#pragma unroll
            for (int ch = 0; ch < 4; ++ch) {
                bf16x8 v;
#pragma unroll
                for (int j = 0; j < 8; ++j)
                    v[j] = f2bf(Wi[(size_t)(ch * 32 + kg * 8 + j) * G4_ + gcol]);
                wiF[c][ch] = v;
            }
            bregv[c] = bvec[gcol];
        }
        // full column sum over all 512 k-rows (reduce across kg groups)
#pragma unroll
        for (int c = 0; c < 2; ++c) {
            whsum[c] += __shfl_xor(whsum[c], 16);
            whsum[c] += __shfl_xor(whsum[c], 32);
        }

        const bool owner = (kg < 2) && (n < 4);
        float cst[2][4], hlast[2][4];
#pragma unroll
        for (int c = 0; c < 2; ++c)
#pragma unroll
            for (int r = 0; r < 4; ++r) {
                cst[c][r] = owner ? init_c[(size_t)(g * 8 + kg * 4 + r) * H_ + colb + c * 4] : 0.f;
                hlast[c][r] = 0.f;
            }

        // obs double-buffer in registers
        f32x4 oraw[8];
        {
            if (n < 8) {
                const float* src = obses + ((size_t)(g * 8 + n) * T_ + 0) * D_ + kg * 8;
#pragma unroll
                for (int ch = 0; ch < 4; ++ch) {
                    oraw[2 * ch]     = *(const f32x4*)(src + ch * 32);
                    oraw[2 * ch + 1] = *(const f32x4*)(src + ch * 32 + 4);
                }
            }
        }

        unsigned long long hq[32];
        if (n >= 8) {
#pragma unroll
            for (int i = 0; i < 32; ++i) hq[i] = 0ull;
        }

        const int CHK  = (R >= 4) ? (R >> 2) : 1;
        const int CHKm = CHK - 1;

        for (int t = 0; t < T_; ++t) {
            // ---- back-pressure vs qs workers (rare) ----
            if ((t & CHKm) == 0) {
                const int need = t + CHK + 1 - R;
                if (need > 0) {
                    bool ok;
                    do {
                        int p = 0x7fffffff;
                        if (l < 4)
                            p = 1 + l + 4 * (int)__hip_atomic_load(ctl + QD_IDX(g, l),
                                    __ATOMIC_RELAXED, __HIP_MEMORY_SCOPE_AGENT);
                        ok = (__all(p >= need) != 0);
                    } while (!ok);
                }
            }

            const float bh  = ((t >> lg2R) & 1) ? -BIAS : BIAS;        // sign of h_t data
            const float bh1 = (((t + 1) >> lg2R) & 1) ? -BIAS : BIAS;  // sign for h_{t+1}

            // ---- x-projection from prefetched obs; prefetch next ----
            bf16x8 obsF[4];
#pragma unroll
            for (int ch = 0; ch < 4; ++ch) {
                bf16x8 v;
                if (n < 8) {
#pragma unroll
                    for (int j = 0; j < 4; ++j) {
                        v[j]     = f2bf(oraw[2 * ch][j]);
                        v[4 + j] = f2bf(oraw[2 * ch + 1][j]);
                    }
                } else {
#pragma unroll
                    for (int j = 0; j < 8; ++j) v[j] = 0;
                }
                obsF[ch] = v;
            }
            if (t + 1 < T_ && n < 8) {
                const float* src = obses + ((size_t)(g * 8 + n) * T_ + (t + 1)) * D_ + kg * 8;
#pragma unroll
                for (int ch = 0; ch < 4; ++ch) {
                    oraw[2 * ch]     = *(const f32x4*)(src + ch * 32);
                    oraw[2 * ch + 1] = *(const f32x4*)(src + ch * 32 + 4);
                }
            }

            // split accumulator chains (2-deep) seeded with bias-corrected breg
            const float s0 = bregv[0] - bh * whsum[0];
            const float s1 = bregv[1] - bh * whsum[1];
            f32x4 a0 = {s0, s0, s0, s0}, b0 = {0.f, 0.f, 0.f, 0.f};
            f32x4 a1 = {s1, s1, s1, s1}, b1 = {0.f, 0.f, 0.f, 0.f};
            a0 = MFMA(obsF[0], wiF[0][0], a0, 0, 0, 0);
            b0 = MFMA(obsF[1], wiF[0][1], b0, 0, 0, 0);
            a0 = MFMA(obsF[2], wiF[0][2], a0, 0, 0, 0);
            b0 = MFMA(obsF[3], wiF[0][3], b0, 0, 0, 0);
            a1 = MFMA(obsF[0], wiF[1][0], a1, 0, 0, 0);
            b1 = MFMA(obsF[1], wiF[1][1], b1, 0, 0, 0);
            a1 = MFMA(obsF[2], wiF[1][2], a1, 0, 0, 0);
            b1 = MFMA(obsF[3], wiF[1][3], b1, 0, 0, 0);

            // ---- poll h_t: data sign == generation parity ----
            // row stride = 512 shorts = 128 u64 (R5 fix: was n*64)
            {
                const unsigned long long* hp =
                    (const unsigned long long*)(hsg + (size_t)(t & Rm) * 4096) + n * 128 + kg * 2;
                const unsigned expd = (bh > 0.f) ? 0u : 0x80008000u;
                bool fresh = true;
                do {
                    if (n < 8) {
                        unsigned bad = 0;
#pragma unroll
                        for (int ch = 0; ch < 16; ++ch) {
                            hq[2 * ch]     = __hip_atomic_load(hp + ch * 8,     __ATOMIC_RELAXED, __HIP_MEMORY_SCOPE_AGENT);
                            hq[2 * ch + 1] = __hip_atomic_load(hp + ch * 8 + 1, __ATOMIC_RELAXED, __HIP_MEMORY_SCOPE_AGENT);
                        }
#pragma unroll
                        for (int i = 0; i < 32; ++i) bad |= ((unsigned)hq[i] ^ expd);
                        fresh = ((bad & 0x80008000u) == 0u);
                    }
                } while (!__all(fresh));
            }

            // ---- recurrent MFMAs (bias folded into seed) ----
#pragma unroll
            for (int ch = 0; ch < 16; ++ch) {
                union { unsigned long long q[2]; bf16x8 v; } u;
                u.q[0] = hq[2 * ch]; u.q[1] = hq[2 * ch + 1];
                if (ch & 1) { b0 = MFMA(u.v, whF[0][ch], b0, 0, 0, 0);
                              b1 = MFMA(u.v, whF[1][ch], b1, 0, 0, 0); }
                else        { a0 = MFMA(u.v, whF[0][ch], a0, 0, 0, 0);
                              a1 = MFMA(u.v, whF[1][ch], a1, 0, 0, 0); }
            }

            // ---- gates, state update, publish h'_{t+1} (u64 stores) ----
            const int slw = (t + 1) & Rm;
#pragma unroll
            for (int c = 0; c < 2; ++c) {
#pragma unroll
                for (int r = 0; r < 4; ++r) {
                    float x  = (c ? (a1[r] + b1[r]) : (a0[r] + b0[r]));
                    float fx = __shfl_xor(x, 4);
                    float gg = __shfl_xor(x, 8);
                    float ox = __shfl_xor(x, 12);
                    float iv = sigm(x), fv = sigm(fx), gv = tanh_(gg), ov = sigm(ox);
                    float nc = fv * cst[c][r] + iv * gv;
                    float nh = ov * tanh_(nc);
                    if (owner) { cst[c][r] = nc; hlast[c][r] = nh; }
                    // pack 4 cols (lanes n=0..3) into one u64, store from n==0
                    unsigned mz = (unsigned)(unsigned short)f2bf(nh + bh1);
                    unsigned oz = (unsigned)__shfl_xor((int)mz, 1);
                    unsigned dw = mz | (oz << 16);
                    unsigned long long far = (unsigned)__shfl_xor((int)dw, 2);
                    unsigned long long qv  = (unsigned long long)dw | (far << 32);
                    if (kg < 2 && n == 0) {
                        unsigned long long* dst = (unsigned long long*)
                            (hsg + (size_t)slw * 4096 + (size_t)(kg * 4 + r) * 512 +
                             (k * 32 + w * 8 + c * 4));
                        __hip_atomic_store(dst, qv, __ATOMIC_RELAXED, __HIP_MEMORY_SCOPE_AGENT);
                    }
                }
            }
            // fire-and-forget: no waitcnt, no flags, no barrier
        }

        // ---- final c, h (fp32 from registers) ----
        if (owner) {
#pragma unroll
            for (int c = 0; c < 2; ++c)
#pragma unroll
                for (int r = 0; r < 4; ++r) {
                    const int brow = g * 8 + kg * 4 + r;
                    out[(size_t)brow * H_ + colb + c * 4] = cst[c][r];
                    out[(size_t)B_ * H_ + (size_t)brow * H_ + colb + c * 4] = hlast[c][r];
                }
        }
    } else {
        // ---------------- qs worker (1 CU per group) ----------------
        const int g = bid - 128;
        short* hsg = hs + (size_t)g * R * 4096;

        bf16x8 wvF[2][16]; float wvsum[2] = {0.f, 0.f}; float bvv[2];
#pragma unroll
        for (int c = 0; c < 2; ++c) {
            const int a  = c * 16 + n;
            const bool va = (a < A_);
#pragma unroll
            for (int ch = 0; ch < 16; ++ch) {
                bf16x8 v;
#pragma unroll
                for (int j = 0; j < 8; ++j) {
                    short sbf = va ? f2bf(Wv[(size_t)(ch * 32 + kg * 8 + j) * A_ + a]) : (short)0;
                    v[j] = sbf; wvsum[c] += bf2f(sbf);
                }
                wvF[c][ch] = v;
            }
            bvv[c] = va ? bv[a] : 0.f;
        }
#pragma unroll
        for (int c = 0; c < 2; ++c) {
            wvsum[c] += __shfl_xor(wvsum[c], 16);
            wvsum[c] += __shfl_xor(wvsum[c], 32);
        }

        unsigned long long hq[32];
        if (n >= 8) {
#pragma unroll
            for (int i = 0; i < 32; ++i) hq[i] = 0ull;
        }

        unsigned cnt = 0;
        for (int s = 1 + w; s <= T_; s += 4) {
            const float bh = ((s >> lg2R) & 1) ? -BIAS : BIAS;
            const unsigned expd = (bh > 0.f) ? 0u : 0x80008000u;
            {
                // row stride = 128 u64 (R5 fix: was n*64)
                const unsigned long long* hp =
                    (const unsigned long long*)(hsg + (size_t)(s & (R - 1)) * 4096) + n * 128 + kg * 2;
                bool fresh = true;
                do {
                    if (n < 8) {
                        unsigned bad = 0;
#pragma unroll
                        for (int ch = 0; ch < 16; ++ch) {
                            hq[2 * ch]     = __hip_atomic_load(hp + ch * 8,     __ATOMIC_RELAXED, __HIP_MEMORY_SCOPE_AGENT);
                            hq[2 * ch + 1] = __hip_atomic_load(hp + ch * 8 + 1, __ATOMIC_RELAXED, __HIP_MEMORY_SCOPE_AGENT);
                        }
#pragma unroll
                        for (int i = 0; i < 32; ++i) bad |= ((unsigned)hq[i] ^ expd);
                        fresh = ((bad & 0x80008000u) == 0u);
                    }
                    if (!__all(fresh)) { __builtin_amdgcn_s_sleep(2); continue; }
                    break;
                } while (true);
            }

            const float q0s = bvv[0] - bh * wvsum[0];
            const float q1s = bvv[1] - bh * wvsum[1];
            f32x4 q0 = {q0s, q0s, q0s, q0s};
            f32x4 q1 = {q1s, q1s, q1s, q1s};
#pragma unroll
            for (int ch = 0; ch < 16; ++ch) {
                union { unsigned long long q[2]; bf16x8 v; } u;
                u.q[0] = hq[2 * ch]; u.q[1] = hq[2 * ch + 1];
                q0 = MFMA(u.v, wvF[0][ch], q0, 0, 0, 0);
                q1 = MFMA(u.v, wvF[1][ch], q1, 0, 0, 0);
            }

            const int tau = s - 1;
#pragma unroll
            for (int c = 0; c < 2; ++c) {
                const int a = c * 16 + n;
                if (kg < 2 && a < A_) {
                    const f32x4 q = c ? q1 : q0;
#pragma unroll
                    for (int r = 0; r < 4; ++r)
                        out[QOFF + ((size_t)(g * 8 + kg * 4 + r) * T_ + tau) * A_ + a] = q[r];
                }
            }
            ++cnt;
            asm volatile("" ::: "memory");
            if (l == 0)
                __hip_atomic_store(ctl + QD_IDX(g, w), cnt, __ATOMIC_RELAXED, __HIP_MEMORY_SCOPE_AGENT);
        }
    }
}

extern "C" void kernel_launch(void* const* d_in, const int* in_sizes, int n_in,
                              void* d_out, int out_size, void* d_ws, size_t ws_size,
                              hipStream_t stream) {
    const float* obses  = (const float*)d_in[0];
    const float* init_c = (const float*)d_in[1];
    const float* init_h = (const float*)d_in[2];
    const float* Wi     = (const float*)d_in[3];
    const float* Wh     = (const float*)d_in[4];
    const float* b      = (const float*)d_in[5];
    const float* Wv     = (const float*)d_in[6];
    const float* bv     = (const float*)d_in[7];
    float* out = (float*)d_out;

    unsigned* ctl = (unsigned*)d_ws;
    short*    hs  = (short*)((char*)d_ws + HS_OFF);

    int R = 512;
    while (R > 8 && (size_t)HS_OFF + (size_t)R * 65536ULL > ws_size) R >>= 1;
    int lg2R = 31 - __builtin_clz((unsigned)R);

    // total ring chunks (uint4 = 8 shorts): 8 groups * R slots * 4096 shorts / 8
    int nchunks = R * 4096;

    hipLaunchKernelGGL(lstm_fill,  dim3(256), dim3(256), 0, stream, ctl, (uint4*)hs, nchunks);
    hipLaunchKernelGGL(lstm_init0, dim3(64),  dim3(256), 0, stream, init_h, hs, R);
    hipLaunchKernelGGL(lstm_main,  dim3(136), dim3(256), 0, stream,
                       obses, init_c, Wi, Wh, b, Wv, bv, out, ctl, hs, R, lg2R);
}

// Round 7
// 40206.180 us; speedup vs baseline: 1.0420x; 1.0420x over previous
//
#include <hip/hip_runtime.h>
#include <stdint.h>
#include <stddef.h>

// LSTMQNetwork: B=64, T=4096, D=128, H=512, A=18
//
// Persistent-RNN, flag-free "data-as-flag" design (R5-verified protocol):
//  - 128 recurrence blocks: 8 groups x 16 CUs; CU owns 32 h-cols.
//    Wh/Wi stationary in VGPRs as bf16 MFMA B-frags.
//  - h published per step into a t-indexed ring (R slots) as h' = h + s*1.5,
//    s = +/-1 by ring generation parity. |h|<1 strictly => sign of every
//    stored bf16 == generation parity => consumers detect freshness from the
//    data's own sign bits; the detecting poll already carries the payload.
//  - bias corrected analytically: h'@W = h@W + 1.5*s*colsum(W), folded into
//    the gate bias (two precomputed variants).
//  - producers: fire-and-forget u64 agent-scope atomic stores; NO fences, NO
//    flags, NO __syncthreads in the loop. obs double-buffered in registers.
//  - 8 worker blocks (4 waves, steps mod 4) compute qs = h@Wv behind the
//    producers; back-pressure via qdone counters every R/4 steps.
//  - R4 fix: lstm_fill stamps the ENTIRE ring 0x8000 (stale for gen 0).
//  - R5 fix: consumer u64 row stride n*128.
//  - R7 changes vs R5 (counter-driven, minimal):
//    (1) R=32 instead of 512: ring 2MB total -> LIC-resident. R5's R=512
//        made worker polls miss to HBM (FETCH 1.45GB) and pace the pipeline.
//    (2) back-pressure corrected: need = t+CHK+4-R (R5's +1 was 3 steps too
//        loose; harmless at R=512, an overwrite race at small R).
//    (3) worker stores its progress counter right after the poll (payload
//        already in regs), taking qs MFMA/stores off the back-pressure path.

#define B_   64
#define T_   4096
#define D_   128
#define H_   512
#define G4_  2048
#define A_   18
#define QOFF (2 * B_ * H_)
#define BIAS 1.5f

typedef float f32x4  __attribute__((ext_vector_type(4)));
typedef short bf16x8 __attribute__((ext_vector_type(8)));
#define MFMA __builtin_amdgcn_mfma_f32_16x16x32_bf16

#define QD_IDX(g,w)  (((g)*4 + (w)) * 16)   // one counter per 64B line
#define CTL_DWORDS   1024
#define HS_OFF       65536                   // byte offset of h ring in ws

__device__ __forceinline__ short f2bf(float x) {
    union { float f; uint32_t u; } v; v.f = x;
    uint32_t r = (v.u + 0x7fffu + ((v.u >> 16) & 1u)) >> 16;  // RNE
    return (short)(uint16_t)r;
}
__device__ __forceinline__ float bf2f(short s) {
    union { uint32_t u; float f; } v; v.u = ((uint32_t)(uint16_t)s) << 16;
    return v.f;
}
__device__ __forceinline__ float sigm(float x) {
    return __builtin_amdgcn_rcpf(1.0f + __builtin_amdgcn_exp2f(-1.4426950408889634f * x));
}
__device__ __forceinline__ float tanh_(float x) {
    return 2.0f * __builtin_amdgcn_rcpf(1.0f + __builtin_amdgcn_exp2f(-2.8853900817779268f * x)) - 1.0f;
}

// stamp ctl=0 and the whole ring stale (0x8000 = -0.0, sign bit set)
__global__ void lstm_fill(unsigned* __restrict__ ctl, uint4* __restrict__ hs4,
                          int nchunks) {
    int idx = blockIdx.x * blockDim.x + threadIdx.x;
    int nt  = gridDim.x * blockDim.x;
    for (int i = idx; i < CTL_DWORDS; i += nt) ctl[i] = 0u;
    const uint4 v = {0x80008000u, 0x80008000u, 0x80008000u, 0x80008000u};
    for (int i = idx; i < nchunks; i += nt) hs4[i] = v;
}

// seed slot 0 with h_0 + 1.5 (generation 0 => positive sign)
__global__ void lstm_init0(const float* __restrict__ init_h,
                           short* __restrict__ hs, int R) {
    int idx = blockIdx.x * blockDim.x + threadIdx.x;
    int nt  = gridDim.x * blockDim.x;
    for (int e = idx; e < B_ * H_; e += nt) {
        int row = e >> 9, col = e & 511;
        int g = row >> 3, r8 = row & 7;
        hs[(size_t)g * R * 4096 + (size_t)r8 * 512 + col] = f2bf(init_h[e] + BIAS);
    }
}

__global__ void __launch_bounds__(256, 1) lstm_main(
    const float* __restrict__ obses, const float* __restrict__ init_c,
    const float* __restrict__ Wi,    const float* __restrict__ Wh,
    const float* __restrict__ bvec,  const float* __restrict__ Wv,
    const float* __restrict__ bv,    float* __restrict__ out,
    unsigned* ctl, short* hs, int R, int lg2R)
{
    const int bid = blockIdx.x;
    const int w   = threadIdx.x >> 6;
    const int l   = threadIdx.x & 63;
    const int n   = l & 15;
    const int kg  = l >> 4;
    const int Rm  = R - 1;

    if (bid < 128) {
        // ---------------- recurrence producer ----------------
        const int g = bid & 7;
        const int k = bid >> 3;            // 0..15
        short* hsg = hs + (size_t)g * R * 4096;

        const int colb = k * 32 + w * 8 + (n & 3);
        const int gate = n >> 2;

        bf16x8 whF[2][16]; bf16x8 wiF[2][4];
        float  whsum[2] = {0.f, 0.f}; float bregv[2];
#pragma unroll
        for (int c = 0; c < 2; ++c) {
            const int gcol = gate * 512 + colb + c * 4;
#pragma unroll
            for (int ch = 0; ch < 16; ++ch) {
                bf16x8 v;
#pragma unroll
                for (int j = 0; j < 8; ++j) {
                    short sbf = f2bf(Wh[(size_t)(ch * 32 + kg * 8 + j) * G4_ + gcol]);
                    v[j] = sbf; whsum[c] += bf2f(sbf);
                }
                whF[c][ch] = v;
            }
#pragma unroll
            for (int ch = 0; ch < 4; ++ch) {
                bf16x8 v;
#pragma unroll
                for (int j = 0; j < 8; ++j)
                    v[j] = f2bf(Wi[(size_t)(ch * 32 + kg * 8 + j) * G4_ + gcol]);
                wiF[c][ch] = v;
            }
            bregv[c] = bvec[gcol];
        }
        // full column sum over all 512 k-rows (reduce across kg groups)
#pragma unroll
        for (int c = 0; c < 2; ++c) {
            whsum[c] += __shfl_xor(whsum[c], 16);
            whsum[c] += __shfl_xor(whsum[c], 32);
        }

        const bool owner = (kg < 2) && (n < 4);
        float cst[2][4], hlast[2][4];
#pragma unroll
        for (int c = 0; c < 2; ++c)
#pragma unroll
            for (int r = 0; r < 4; ++r) {
                cst[c][r] = owner ? init_c[(size_t)(g * 8 + kg * 4 + r) * H_ + colb + c * 4] : 0.f;
                hlast[c][r] = 0.f;
            }

        // obs double-buffer in registers
        f32x4 oraw[8];
        {
            if (n < 8) {
                const float* src = obses + ((size_t)(g * 8 + n) * T_ + 0) * D_ + kg * 8;
#pragma unroll
                for (int ch = 0; ch < 4; ++ch) {
                    oraw[2 * ch]     = *(const f32x4*)(src + ch * 32);
                    oraw[2 * ch + 1] = *(const f32x4*)(src + ch * 32 + 4);
                }
            }
        }

        unsigned long long hq[32];
        if (n >= 8) {
#pragma unroll
            for (int i = 0; i < 32; ++i) hq[i] = 0ull;
        }

        const int CHK  = R >> 2;
        const int CHKm = CHK - 1;

        for (int t = 0; t < T_; ++t) {
            // ---- back-pressure vs qs workers ----
            if ((t & CHKm) == 0) {
                // producer writes slots (t+1)..(t+CHK) before next check,
                // overwriting h(t+1-R)..(t+CHK-R). Worker wave w's counter c4
                // implies consumption of all its steps <= (1+w+4*c4)-4.
                // Require p >= t+CHK-R+4.
                const int need = t + CHK + 4 - R;
                if (need > 0) {
                    bool ok;
                    do {
                        int p = 0x7fffffff;
                        if (l < 4)
                            p = 1 + l + 4 * (int)__hip_atomic_load(ctl + QD_IDX(g, l),
                                    __ATOMIC_RELAXED, __HIP_MEMORY_SCOPE_AGENT);
                        ok = (__all(p >= need) != 0);
                    } while (!ok);
                }
            }

            const float bh  = ((t >> lg2R) & 1) ? -BIAS : BIAS;        // sign of h_t data
            const float bh1 = (((t + 1) >> lg2R) & 1) ? -BIAS : BIAS;  // sign for h_{t+1}

            // ---- x-projection from prefetched obs; prefetch next ----
            bf16x8 obsF[4];
#pragma unroll
            for (int ch = 0; ch < 4; ++ch) {
                bf16x8 v;
                if (n < 8) {
#pragma unroll
                    for (int j = 0; j < 4; ++j) {
                        v[j]     = f2bf(oraw[2 * ch][j]);
                        v[4 + j] = f2bf(oraw[2 * ch + 1][j]);
                    }
                } else {
#pragma unroll
                    for (int j = 0; j < 8; ++j) v[j] = 0;
                }
                obsF[ch] = v;
            }
            if (t + 1 < T_ && n < 8) {
                const float* src = obses + ((size_t)(g * 8 + n) * T_ + (t + 1)) * D_ + kg * 8;
#pragma unroll
                for (int ch = 0; ch < 4; ++ch) {
                    oraw[2 * ch]     = *(const f32x4*)(src + ch * 32);
                    oraw[2 * ch + 1] = *(const f32x4*)(src + ch * 32 + 4);
                }
            }

            // split accumulator chains (2-deep) seeded with bias-corrected breg
            const float s0 = bregv[0] - bh * whsum[0];
            const float s1 = bregv[1] - bh * whsum[1];
            f32x4 a0 = {s0, s0, s0, s0}, b0 = {0.f, 0.f, 0.f, 0.f};
            f32x4 a1 = {s1, s1, s1, s1}, b1 = {0.f, 0.f, 0.f, 0.f};
            a0 = MFMA(obsF[0], wiF[0][0], a0, 0, 0, 0);
            b0 = MFMA(obsF[1], wiF[0][1], b0, 0, 0, 0);
            a0 = MFMA(obsF[2], wiF[0][2], a0, 0, 0, 0);
            b0 = MFMA(obsF[3], wiF[0][3], b0, 0, 0, 0);
            a1 = MFMA(obsF[0], wiF[1][0], a1, 0, 0, 0);
            b1 = MFMA(obsF[1], wiF[1][1], b1, 0, 0, 0);
            a1 = MFMA(obsF[2], wiF[1][2], a1, 0, 0, 0);
            b1 = MFMA(obsF[3], wiF[1][3], b1, 0, 0, 0);

            // ---- poll h_t: data sign == generation parity ----
            // row stride = 512 shorts = 128 u64
            {
                const unsigned long long* hp =
                    (const unsigned long long*)(hsg + (size_t)(t & Rm) * 4096) + n * 128 + kg * 2;
                const unsigned expd = (bh > 0.f) ? 0u : 0x80008000u;
                bool fresh = true;
                do {
                    if (n < 8) {
                        unsigned bad = 0;
#pragma unroll
                        for (int ch = 0; ch < 16; ++ch) {
                            hq[2 * ch]     = __hip_atomic_load(hp + ch * 8,     __ATOMIC_RELAXED, __HIP_MEMORY_SCOPE_AGENT);
                            hq[2 * ch + 1] = __hip_atomic_load(hp + ch * 8 + 1, __ATOMIC_RELAXED, __HIP_MEMORY_SCOPE_AGENT);
                        }
#pragma unroll
                        for (int i = 0; i < 32; ++i) bad |= ((unsigned)hq[i] ^ expd);
                        fresh = ((bad & 0x80008000u) == 0u);
                    }
                } while (!__all(fresh));
            }

            // ---- recurrent MFMAs (bias folded into seed) ----
#pragma unroll
            for (int ch = 0; ch < 16; ++ch) {
                union { unsigned long long q[2]; bf16x8 v; } u;
                u.q[0] = hq[2 * ch]; u.q[1] = hq[2 * ch + 1];
                if (ch & 1) { b0 = MFMA(u.v, whF[0][ch], b0, 0, 0, 0);
                              b1 = MFMA(u.v, whF[1][ch], b1, 0, 0, 0); }
                else        { a0 = MFMA(u.v, whF[0][ch], a0, 0, 0, 0);
                              a1 = MFMA(u.v, whF[1][ch], a1, 0, 0, 0); }
            }

            // ---- gates, state update, publish h'_{t+1} (u64 stores) ----
            const int slw = (t + 1) & Rm;
#pragma unroll
            for (int c = 0; c < 2; ++c) {
#pragma unroll
                for (int r = 0; r < 4; ++r) {
                    float x  = (c ? (a1[r] + b1[r]) : (a0[r] + b0[r]));
                    float fx = __shfl_xor(x, 4);
                    float gg = __shfl_xor(x, 8);
                    float ox = __shfl_xor(x, 12);
                    float iv = sigm(x), fv = sigm(fx), gv = tanh_(gg), ov = sigm(ox);
                    float nc = fv * cst[c][r] + iv * gv;
                    float nh = ov * tanh_(nc);
                    if (owner) { cst[c][r] = nc; hlast[c][r] = nh; }
                    // pack 4 cols (lanes n=0..3) into one u64, store from n==0
                    unsigned mz = (unsigned)(unsigned short)f2bf(nh + bh1);
                    unsigned oz = (unsigned)__shfl_xor((int)mz, 1);
                    unsigned dw = mz | (oz << 16);
                    unsigned long long far = (unsigned)__shfl_xor((int)dw, 2);
                    unsigned long long qv  = (unsigned long long)dw | (far << 32);
                    if (kg < 2 && n == 0) {
                        unsigned long long* dst = (unsigned long long*)
                            (hsg + (size_t)slw * 4096 + (size_t)(kg * 4 + r) * 512 +
                             (k * 32 + w * 8 + c * 4));
                        __hip_atomic_store(dst, qv, __ATOMIC_RELAXED, __HIP_MEMORY_SCOPE_AGENT);
                    }
                }
            }
            // fire-and-forget: no waitcnt, no flags, no barrier
        }

        // ---- final c, h (fp32 from registers) ----
        if (owner) {
#pragma unroll
            for (int c = 0; c < 2; ++c)
#pragma unroll
                for (int r = 0; r < 4; ++r) {
                    const int brow = g * 8 + kg * 4 + r;
                    out[(size_t)brow * H_ + colb + c * 4] = cst[c][r];
                    out[(size_t)B_ * H_ + (size_t)brow * H_ + colb + c * 4] = hlast[c][r];
                }
        }
    } else {
        // ---------------- qs worker (1 CU per group) ----------------
        const int g = bid - 128;
        short* hsg = hs + (size_t)g * R * 4096;

        bf16x8 wvF[2][16]; float wvsum[2] = {0.f, 0.f}; float bvv[2];
#pragma unroll
        for (int c = 0; c < 2; ++c) {
            const int a  = c * 16 + n;
            const bool va = (a < A_);
#pragma unroll
            for (int ch = 0; ch < 16; ++ch) {
                bf16x8 v;
#pragma unroll
                for (int j = 0; j < 8; ++j) {
                    short sbf = va ? f2bf(Wv[(size_t)(ch * 32 + kg * 8 + j) * A_ + a]) : (short)0;
                    v[j] = sbf; wvsum[c] += bf2f(sbf);
                }
                wvF[c][ch] = v;
            }
            bvv[c] = va ? bv[a] : 0.f;
        }
#pragma unroll
        for (int c = 0; c < 2; ++c) {
            wvsum[c] += __shfl_xor(wvsum[c], 16);
            wvsum[c] += __shfl_xor(wvsum[c], 32);
        }

        unsigned long long hq[32];
        if (n >= 8) {
#pragma unroll
            for (int i = 0; i < 32; ++i) hq[i] = 0ull;
        }

        unsigned cnt = 0;
        for (int s = 1 + w; s <= T_; s += 4) {
            const float bh = ((s >> lg2R) & 1) ? -BIAS : BIAS;
            const unsigned expd = (bh > 0.f) ? 0u : 0x80008000u;
            {
                // row stride = 128 u64
                const unsigned long long* hp =
                    (const unsigned long long*)(hsg + (size_t)(s & (R - 1)) * 4096) + n * 128 + kg * 2;
                bool fresh = true;
                do {
                    if (n < 8) {
                        unsigned bad = 0;
#pragma unroll
                        for (int ch = 0; ch < 16; ++ch) {
                            hq[2 * ch]     = __hip_atomic_load(hp + ch * 8,     __ATOMIC_RELAXED, __HIP_MEMORY_SCOPE_AGENT);
                            hq[2 * ch + 1] = __hip_atomic_load(hp + ch * 8 + 1, __ATOMIC_RELAXED, __HIP_MEMORY_SCOPE_AGENT);
                        }
#pragma unroll
                        for (int i = 0; i < 32; ++i) bad |= ((unsigned)hq[i] ^ expd);
                        fresh = ((bad & 0x80008000u) == 0u);
                    }
                    if (!__all(fresh)) { __builtin_amdgcn_s_sleep(2); continue; }
                    break;
                } while (true);
            }

            // progress counter published IMMEDIATELY (payload is in regs) —
            // takes qs MFMA/stores off the producers' back-pressure path
            ++cnt;
            asm volatile("" ::: "memory");
            if (l == 0)
                __hip_atomic_store(ctl + QD_IDX(g, w), cnt, __ATOMIC_RELAXED, __HIP_MEMORY_SCOPE_AGENT);

            const float q0s = bvv[0] - bh * wvsum[0];
            const float q1s = bvv[1] - bh * wvsum[1];
            f32x4 q0 = {q0s, q0s, q0s, q0s};
            f32x4 q1 = {q1s, q1s, q1s, q1s};
#pragma unroll
            for (int ch = 0; ch < 16; ++ch) {
                union { unsigned long long q[2]; bf16x8 v; } u;
                u.q[0] = hq[2 * ch]; u.q[1] = hq[2 * ch + 1];
                q0 = MFMA(u.v, wvF[0][ch], q0, 0, 0, 0);
                q1 = MFMA(u.v, wvF[1][ch], q1, 0, 0, 0);
            }

            const int tau = s - 1;
#pragma unroll
            for (int c = 0; c < 2; ++c) {
                const int a = c * 16 + n;
                if (kg < 2 && a < A_) {
                    const f32x4 q = c ? q1 : q0;
#pragma unroll
                    for (int r = 0; r < 4; ++r)
                        out[QOFF + ((size_t)(g * 8 + kg * 4 + r) * T_ + tau) * A_ + a] = q[r];
                }
            }
        }
    }
}

extern "C" void kernel_launch(void* const* d_in, const int* in_sizes, int n_in,
                              void* d_out, int out_size, void* d_ws, size_t ws_size,
                              hipStream_t stream) {
    const float* obses  = (const float*)d_in[0];
    const float* init_c = (const float*)d_in[1];
    const float* init_h = (const float*)d_in[2];
    const float* Wi     = (const float*)d_in[3];
    const float* Wh     = (const float*)d_in[4];
    const float* b      = (const float*)d_in[5];
    const float* Wv     = (const float*)d_in[6];
    const float* bv     = (const float*)d_in[7];
    float* out = (float*)d_out;

    unsigned* ctl = (unsigned*)d_ws;
    short*    hs  = (short*)((char*)d_ws + HS_OFF);

    // R=32: ring = 8 groups * 32 slots * 8KB = 2MB -> LIC-resident.
    int R = 32;
    while (R > 8 && (size_t)HS_OFF + 8ull * R * 8192ull > ws_size) R >>= 1;
    int lg2R = 31 - __builtin_clz((unsigned)R);

    // ring chunks (uint4 = 8 shorts): 8 groups * R * 8192 B / 16 B
    int nchunks = R * 4096;

    hipLaunchKernelGGL(lstm_fill,  dim3(256), dim3(256), 0, stream, ctl, (uint4*)hs, nchunks);
    hipLaunchKernelGGL(lstm_init0, dim3(64),  dim3(256), 0, stream, init_h, hs, R);
    hipLaunchKernelGGL(lstm_main,  dim3(136), dim3(256), 0, stream,
                       obses, init_c, Wi, Wh, b, Wv, bv, out, ctl, hs, R, lg2R);
}

// Round 10
// 20540.773 us; speedup vs baseline: 2.0396x; 1.9574x over previous
//
#include <hip/hip_runtime.h>
#include <stdint.h>
#include <stddef.h>

// LSTMQNetwork: B=64, T=4096, D=128, H=512, A=18
//
// R10: sentinel protocol — hybrid of the two VERIFIED designs.
//   R2 (22ms, passed): flag+fence exchange. Cost: release/acquire cache
//     maintenance + __syncthreads every step.
//   R7 (40ms, passed): fence-free payload-sign polling. Cost: 8KB uncached
//     re-read per spin iteration.
//   R10 keeps R7's fence-free relaxed-atomic payload transfer but spins on
//   per-wave SENTINELS (4B per lane per spin, 64 sentinels/group = one per
//   consumer lane, each on its own 64B line), reading the payload exactly
//   once after detection. Ordering: payload u64 atomic stores -> wave-level
//   s_waitcnt vmcnt(0) (ack at coherence point; R2-proven) -> sentinel
//   store t+1. No fences, no __syncthreads, no parity encoding -> h stored
//   RAW bf16 (better quantization than the +1.5 trick).
//   XCD-local branch abandoned (R6/R8/R9: 2 failures + 1 container kill).
//
//  - 128 producers: 8 groups (bid&7) x 16 CUs, CU owns 32 h-cols; Wh/Wi
//    stationary in VGPRs (R2/R5/R7-proven layout, byte-identical publishes).
//  - 8 qs workers (bid 128..135): 4 waves, steps mod 4; progress counters
//    with R7's back-pressure formula (need = t+CHK+4-R), R=32, CHK=8.

#define B_   64
#define T_   4096
#define D_   128
#define H_   512
#define G4_  2048
#define A_   18
#define QOFF (2 * B_ * H_)

typedef float f32x4  __attribute__((ext_vector_type(4)));
typedef short bf16x8 __attribute__((ext_vector_type(8)));
#define MFMA __builtin_amdgcn_mfma_f32_16x16x32_bf16

#define SEN_IDX(g,i) ((((g) * 64) + (i)) * 16)        // sentinel dword, 1/64B line
#define QD_IDX(g,w)  (8192 + (((g) * 4) + (w)) * 16)  // worker progress
#define CTL_DWORDS   16384                            // 64 KiB, zeroed per call
#define HS_OFF       65536                            // ring byte offset in ws

__device__ __forceinline__ short f2bf(float x) {
    union { float f; uint32_t u; } v; v.f = x;
    uint32_t r = (v.u + 0x7fffu + ((v.u >> 16) & 1u)) >> 16;  // RNE
    return (short)(uint16_t)r;
}
__device__ __forceinline__ float sigm(float x) {
    return __builtin_amdgcn_rcpf(1.0f + __builtin_amdgcn_exp2f(-1.4426950408889634f * x));
}
__device__ __forceinline__ float tanh_(float x) {
    return 2.0f * __builtin_amdgcn_rcpf(1.0f + __builtin_amdgcn_exp2f(-2.8853900817779268f * x)) - 1.0f;
}

// zero the control region (sentinels + worker progress)
__global__ void lstm_fill(unsigned* __restrict__ ctl) {
    int idx = blockIdx.x * blockDim.x + threadIdx.x;
    int nt  = gridDim.x * blockDim.x;
    for (int i = idx; i < CTL_DWORDS; i += nt) ctl[i] = 0u;
}

// seed ring slot 0 with raw h_0
__global__ void lstm_init0(const float* __restrict__ init_h,
                           short* __restrict__ hs, int R) {
    int idx = blockIdx.x * blockDim.x + threadIdx.x;
    int nt  = gridDim.x * blockDim.x;
    for (int e = idx; e < B_ * H_; e += nt) {
        int row = e >> 9, col = e & 511;
        int g = row >> 3, r8 = row & 7;
        hs[(size_t)g * R * 4096 + (size_t)r8 * 512 + col] = f2bf(init_h[e]);
    }
}

__global__ void __launch_bounds__(256, 1) lstm_main(
    const float* __restrict__ obses, const float* __restrict__ init_c,
    const float* __restrict__ Wi,    const float* __restrict__ Wh,
    const float* __restrict__ bvec,  const float* __restrict__ Wv,
    const float* __restrict__ bv,    float* __restrict__ out,
    unsigned* ctl, short* hs, int R)
{
    const int bid = blockIdx.x;
    const int w   = threadIdx.x >> 6;
    const int l   = threadIdx.x & 63;
    const int n   = l & 15;
    const int kg  = l >> 4;
    const int Rm  = R - 1;

    if (bid < 128) {
        // ---------------- recurrence producer ----------------
        const int g = bid & 7;
        const int k = bid >> 3;            // 0..15
        short* hsg = hs + (size_t)g * R * 4096;

        const int colb = k * 32 + w * 8 + (n & 3);
        const int gate = n >> 2;

        bf16x8 whF[2][16]; bf16x8 wiF[2][4]; float bregv[2];
#pragma unroll
        for (int c = 0; c < 2; ++c) {
            const int gcol = gate * 512 + colb + c * 4;
#pragma unroll
            for (int ch = 0; ch < 16; ++ch) {
                bf16x8 v;
#pragma unroll
                for (int j = 0; j < 8; ++j)
                    v[j] = f2bf(Wh[(size_t)(ch * 32 + kg * 8 + j) * G4_ + gcol]);
                whF[c][ch] = v;
            }
#pragma unroll
            for (int ch = 0; ch < 4; ++ch) {
                bf16x8 v;
#pragma unroll
                for (int j = 0; j < 8; ++j)
                    v[j] = f2bf(Wi[(size_t)(ch * 32 + kg * 8 + j) * G4_ + gcol]);
                wiF[c][ch] = v;
            }
            bregv[c] = bvec[gcol];
        }

        const bool owner = (kg < 2) && (n < 4);
        float cst[2][4], hlast[2][4];
#pragma unroll
        for (int c = 0; c < 2; ++c)
#pragma unroll
            for (int r = 0; r < 4; ++r) {
                cst[c][r] = owner ? init_c[(size_t)(g * 8 + kg * 4 + r) * H_ + colb + c * 4] : 0.f;
                hlast[c][r] = 0.f;
            }

        // obs double-buffer in registers
        f32x4 oraw[8];
        if (n < 8) {
            const float* src = obses + ((size_t)(g * 8 + n) * T_ + 0) * D_ + kg * 8;
#pragma unroll
            for (int ch = 0; ch < 4; ++ch) {
                oraw[2 * ch]     = *(const f32x4*)(src + ch * 32);
                oraw[2 * ch + 1] = *(const f32x4*)(src + ch * 32 + 4);
            }
        }

        unsigned long long hq[32];
        if (n >= 8) {
#pragma unroll
            for (int i = 0; i < 32; ++i) hq[i] = 0ull;
        }

        const int CHK  = R >> 2;
        const int CHKm = CHK - 1;
        const int senp = SEN_IDX(g, k * 4 + w);   // this wave's sentinel

        for (int t = 0; t < T_; ++t) {
            // ---- back-pressure vs qs workers (rare) ----
            if ((t & CHKm) == 0) {
                const int need = t + CHK + 4 - R;
                if (need > 0) {
                    bool ok;
                    do {
                        int p = 0x7fffffff;
                        if (l < 4)
                            p = 1 + l + 4 * (int)__hip_atomic_load(ctl + QD_IDX(g, l),
                                    __ATOMIC_RELAXED, __HIP_MEMORY_SCOPE_AGENT);
                        ok = (__all(p >= need) != 0);
                    } while (!ok);
                }
            }

            // ---- x-projection from prefetched obs; prefetch next ----
            bf16x8 obsF[4];
#pragma unroll
            for (int ch = 0; ch < 4; ++ch) {
                bf16x8 v;
                if (n < 8) {
#pragma unroll
                    for (int j = 0; j < 4; ++j) {
                        v[j]     = f2bf(oraw[2 * ch][j]);
                        v[4 + j] = f2bf(oraw[2 * ch + 1][j]);
                    }
                } else {
#pragma unroll
                    for (int j = 0; j < 8; ++j) v[j] = 0;
                }
                obsF[ch] = v;
            }
            if (t + 1 < T_ && n < 8) {
                const float* src = obses + ((size_t)(g * 8 + n) * T_ + (t + 1)) * D_ + kg * 8;
#pragma unroll
                for (int ch = 0; ch < 4; ++ch) {
                    oraw[2 * ch]     = *(const f32x4*)(src + ch * 32);
                    oraw[2 * ch + 1] = *(const f32x4*)(src + ch * 32 + 4);
                }
            }

            f32x4 a0 = {bregv[0], bregv[0], bregv[0], bregv[0]};
            f32x4 a1 = {bregv[1], bregv[1], bregv[1], bregv[1]};
            f32x4 b0 = {0.f, 0.f, 0.f, 0.f}, b1 = {0.f, 0.f, 0.f, 0.f};
            a0 = MFMA(obsF[0], wiF[0][0], a0, 0, 0, 0);
            b0 = MFMA(obsF[1], wiF[0][1], b0, 0, 0, 0);
            a0 = MFMA(obsF[2], wiF[0][2], a0, 0, 0, 0);
            b0 = MFMA(obsF[3], wiF[0][3], b0, 0, 0, 0);
            a1 = MFMA(obsF[0], wiF[1][0], a1, 0, 0, 0);
            b1 = MFMA(obsF[1], wiF[1][1], b1, 0, 0, 0);
            a1 = MFMA(obsF[2], wiF[1][2], a1, 0, 0, 0);
            b1 = MFMA(obsF[3], wiF[1][3], b1, 0, 0, 0);

            // ---- wait for h_t: one 4B sentinel per lane ----
            if (t > 0) {
                const unsigned tgt = (unsigned)t;
                bool ready;
                do {
                    unsigned v = __hip_atomic_load(ctl + SEN_IDX(g, l),
                                     __ATOMIC_RELAXED, __HIP_MEMORY_SCOPE_AGENT);
                    ready = (__all(v >= tgt) != 0);
                } while (!ready);
            }

            // ---- read h_t payload ONCE (relaxed agent atomics) ----
            {
                const unsigned long long* hp =
                    (const unsigned long long*)(hsg + (size_t)(t & Rm) * 4096) + n * 128 + kg * 2;
                if (n < 8) {
#pragma unroll
                    for (int ch = 0; ch < 16; ++ch) {
                        hq[2 * ch]     = __hip_atomic_load(hp + ch * 8,     __ATOMIC_RELAXED, __HIP_MEMORY_SCOPE_AGENT);
                        hq[2 * ch + 1] = __hip_atomic_load(hp + ch * 8 + 1, __ATOMIC_RELAXED, __HIP_MEMORY_SCOPE_AGENT);
                    }
                }
            }

            // ---- recurrent MFMAs ----
#pragma unroll
            for (int ch = 0; ch < 16; ++ch) {
                union { unsigned long long q[2]; bf16x8 v; } u;
                u.q[0] = hq[2 * ch]; u.q[1] = hq[2 * ch + 1];
                if (ch & 1) { b0 = MFMA(u.v, whF[0][ch], b0, 0, 0, 0);
                              b1 = MFMA(u.v, whF[1][ch], b1, 0, 0, 0); }
                else        { a0 = MFMA(u.v, whF[0][ch], a0, 0, 0, 0);
                              a1 = MFMA(u.v, whF[1][ch], a1, 0, 0, 0); }
            }

            // ---- gates, state update, publish raw h_{t+1} (u64 stores) ----
            const int slw = (t + 1) & Rm;
#pragma unroll
            for (int c = 0; c < 2; ++c) {
#pragma unroll
                for (int r = 0; r < 4; ++r) {
                    float x  = (c ? (a1[r] + b1[r]) : (a0[r] + b0[r]));
                    float fx = __shfl_xor(x, 4);
                    float gg = __shfl_xor(x, 8);
                    float ox = __shfl_xor(x, 12);
                    float iv = sigm(x), fv = sigm(fx), gv = tanh_(gg), ov = sigm(ox);
                    float nc = fv * cst[c][r] + iv * gv;
                    float nh = ov * tanh_(nc);
                    if (owner) { cst[c][r] = nc; hlast[c][r] = nh; }
                    unsigned mz = (unsigned)(unsigned short)f2bf(nh);
                    unsigned oz = (unsigned)__shfl_xor((int)mz, 1);
                    unsigned dw = mz | (oz << 16);
                    unsigned long long far = (unsigned)__shfl_xor((int)dw, 2);
                    unsigned long long qv  = (unsigned long long)dw | (far << 32);
                    if (kg < 2 && n == 0) {
                        unsigned long long* dst = (unsigned long long*)
                            (hsg + (size_t)slw * 4096 + (size_t)(kg * 4 + r) * 512 +
                             (k * 32 + w * 8 + c * 4));
                        __hip_atomic_store(dst, qv, __ATOMIC_RELAXED, __HIP_MEMORY_SCOPE_AGENT);
                    }
                }
            }
            // payload acked at coherence point, THEN sentinel (R2-proven order)
            asm volatile("s_waitcnt vmcnt(0)" ::: "memory");
            if (l == 0)
                __hip_atomic_store(ctl + senp, (unsigned)(t + 1),
                                   __ATOMIC_RELAXED, __HIP_MEMORY_SCOPE_AGENT);
        }

        // ---- final c, h (fp32 from registers) ----
        if (owner) {
#pragma unroll
            for (int c = 0; c < 2; ++c)
#pragma unroll
                for (int r = 0; r < 4; ++r) {
                    const int brow = g * 8 + kg * 4 + r;
                    out[(size_t)brow * H_ + colb + c * 4] = cst[c][r];
                    out[(size_t)B_ * H_ + (size_t)brow * H_ + colb + c * 4] = hlast[c][r];
                }
        }
    } else {
        // ---------------- qs worker (1 CU per group) ----------------
        const int g = bid - 128;
        short* hsg = hs + (size_t)g * R * 4096;

        bf16x8 wvF[2][16]; float bvv[2];
#pragma unroll
        for (int c = 0; c < 2; ++c) {
            const int a  = c * 16 + n;
            const bool va = (a < A_);
#pragma unroll
            for (int ch = 0; ch < 16; ++ch) {
                bf16x8 v;
#pragma unroll
                for (int j = 0; j < 8; ++j)
                    v[j] = va ? f2bf(Wv[(size_t)(ch * 32 + kg * 8 + j) * A_ + a]) : (short)0;
                wvF[c][ch] = v;
            }
            bvv[c] = va ? bv[a] : 0.f;
        }

        unsigned long long hq[32];
        if (n >= 8) {
#pragma unroll
            for (int i = 0; i < 32; ++i) hq[i] = 0ull;
        }

        unsigned cnt = 0;
        for (int s = 1 + w; s <= T_; s += 4) {
            // ---- wait for h_s: one 4B sentinel per lane ----
            {
                const unsigned tgt = (unsigned)s;
                bool ready;
                do {
                    unsigned v = __hip_atomic_load(ctl + SEN_IDX(g, l),
                                     __ATOMIC_RELAXED, __HIP_MEMORY_SCOPE_AGENT);
                    ready = (__all(v >= tgt) != 0);
                    if (!ready) __builtin_amdgcn_s_sleep(2);
                } while (!ready);
            }

            // ---- read payload once ----
            {
                const unsigned long long* hp =
                    (const unsigned long long*)(hsg + (size_t)(s & (R - 1)) * 4096) + n * 128 + kg * 2;
                if (n < 8) {
#pragma unroll
                    for (int ch = 0; ch < 16; ++ch) {
                        hq[2 * ch]     = __hip_atomic_load(hp + ch * 8,     __ATOMIC_RELAXED, __HIP_MEMORY_SCOPE_AGENT);
                        hq[2 * ch + 1] = __hip_atomic_load(hp + ch * 8 + 1, __ATOMIC_RELAXED, __HIP_MEMORY_SCOPE_AGENT);
                    }
                }
            }
            // loads complete before declaring progress (slot may be reused)
            asm volatile("s_waitcnt vmcnt(0)" ::: "memory");
            ++cnt;
            if (l == 0)
                __hip_atomic_store(ctl + QD_IDX(g, w), cnt,
                                   __ATOMIC_RELAXED, __HIP_MEMORY_SCOPE_AGENT);

            f32x4 q0 = {bvv[0], bvv[0], bvv[0], bvv[0]};
            f32x4 q1 = {bvv[1], bvv[1], bvv[1], bvv[1]};
#pragma unroll
            for (int ch = 0; ch < 16; ++ch) {
                union { unsigned long long q[2]; bf16x8 v; } u;
                u.q[0] = hq[2 * ch]; u.q[1] = hq[2 * ch + 1];
                q0 = MFMA(u.v, wvF[0][ch], q0, 0, 0, 0);
                q1 = MFMA(u.v, wvF[1][ch], q1, 0, 0, 0);
            }

            const int tau = s - 1;
#pragma unroll
            for (int c = 0; c < 2; ++c) {
                const int a = c * 16 + n;
                if (kg < 2 && a < A_) {
                    const f32x4 q = c ? q1 : q0;
#pragma unroll
                    for (int r = 0; r < 4; ++r)
                        out[QOFF + ((size_t)(g * 8 + kg * 4 + r) * T_ + tau) * A_ + a] = q[r];
                }
            }
        }
    }
}

extern "C" void kernel_launch(void* const* d_in, const int* in_sizes, int n_in,
                              void* d_out, int out_size, void* d_ws, size_t ws_size,
                              hipStream_t stream) {
    const float* obses  = (const float*)d_in[0];
    const float* init_c = (const float*)d_in[1];
    const float* init_h = (const float*)d_in[2];
    const float* Wi     = (const float*)d_in[3];
    const float* Wh     = (const float*)d_in[4];
    const float* b      = (const float*)d_in[5];
    const float* Wv     = (const float*)d_in[6];
    const float* bv     = (const float*)d_in[7];
    float* out = (float*)d_out;

    unsigned* ctl = (unsigned*)d_ws;
    short*    hs  = (short*)((char*)d_ws + HS_OFF);

    int R = 32;
    while (R > 8 && (size_t)HS_OFF + 8ull * R * 8192ull > ws_size) R >>= 1;

    hipLaunchKernelGGL(lstm_fill,  dim3(64),  dim3(256), 0, stream, ctl);
    hipLaunchKernelGGL(lstm_init0, dim3(64),  dim3(256), 0, stream, init_h, hs, R);
    hipLaunchKernelGGL(lstm_main,  dim3(136), dim3(256), 0, stream,
                       obses, init_c, Wi, Wh, b, Wv, bv, out, ctl, hs, R);
}

// Round 11
// 15753.926 us; speedup vs baseline: 2.6594x; 1.3039x over previous
//
#include <hip/hip_runtime.h>
#include <stdint.h>
#include <stddef.h>

// LSTMQNetwork: B=64, T=4096, D=128, H=512, A=18
//
// R11 = R10 (sentinel protocol, 20.5ms, passed) + per-CU deduplication of
// all redundant LIC traffic. Wire protocol byte-identical to R10; changes
// are intra-block only:
//  (1) ONE sentinel per CU (16/group, was 64): per-wave vmcnt(0) ->
//      __syncthreads -> thread 0 stores sentinel t+1.
//  (2) only wave 0 polls the 16 sentinels (16 lines/iter, was 4 waves x 64);
//      __syncthreads releases the whole CU.
//  (3) h payload read ONCE per CU: each wave loads a 2KB quarter (4 u64/lane,
//      relaxed agent atomics, R10-proven path), stages into LDS (row stride
//      132 u64 -> <=2-way bank aliasing = free), __syncthreads, MFMA B-frags
//      ds_read from LDS with R10's exact index math (n*132+ch*8+kg*2 vs
//      global n*128+ch*8+kg*2). Kills the 64-VGPR hq array.
// Theory: R10's ~3x step-time inflation over the serial chain was LIC
// congestion from 4x redundant payload reads + 16x redundant sentinel polls.

#define B_   64
#define T_   4096
#define D_   128
#define H_   512
#define G4_  2048
#define A_   18
#define QOFF (2 * B_ * H_)

typedef float f32x4  __attribute__((ext_vector_type(4)));
typedef short bf16x8 __attribute__((ext_vector_type(8)));
typedef unsigned long long u64;
#define MFMA __builtin_amdgcn_mfma_f32_16x16x32_bf16

#define SEN_IDX(g,k) ((((g) * 16) + (k)) * 16)        // CU sentinel, 1/64B line
#define QD_IDX(g,w)  (8192 + (((g) * 4) + (w)) * 16)  // worker progress
#define CTL_DWORDS   16384                            // 64 KiB, zeroed per call
#define HS_OFF       65536                            // ring byte offset in ws

__device__ __forceinline__ short f2bf(float x) {
    union { float f; uint32_t u; } v; v.f = x;
    uint32_t r = (v.u + 0x7fffu + ((v.u >> 16) & 1u)) >> 16;  // RNE
    return (short)(uint16_t)r;
}
__device__ __forceinline__ float sigm(float x) {
    return __builtin_amdgcn_rcpf(1.0f + __builtin_amdgcn_exp2f(-1.4426950408889634f * x));
}
__device__ __forceinline__ float tanh_(float x) {
    return 2.0f * __builtin_amdgcn_rcpf(1.0f + __builtin_amdgcn_exp2f(-2.8853900817779268f * x)) - 1.0f;
}

// zero the control region (sentinels + worker progress)
__global__ void lstm_fill(unsigned* __restrict__ ctl) {
    int idx = blockIdx.x * blockDim.x + threadIdx.x;
    int nt  = gridDim.x * blockDim.x;
    for (int i = idx; i < CTL_DWORDS; i += nt) ctl[i] = 0u;
}

// seed ring slot 0 with raw h_0
__global__ void lstm_init0(const float* __restrict__ init_h,
                           short* __restrict__ hs, int R) {
    int idx = blockIdx.x * blockDim.x + threadIdx.x;
    int nt  = gridDim.x * blockDim.x;
    for (int e = idx; e < B_ * H_; e += nt) {
        int row = e >> 9, col = e & 511;
        int g = row >> 3, r8 = row & 7;
        hs[(size_t)g * R * 4096 + (size_t)r8 * 512 + col] = f2bf(init_h[e]);
    }
}

__global__ void __launch_bounds__(256, 1) lstm_main(
    const float* __restrict__ obses, const float* __restrict__ init_c,
    const float* __restrict__ Wi,    const float* __restrict__ Wh,
    const float* __restrict__ bvec,  const float* __restrict__ Wv,
    const float* __restrict__ bv,    float* __restrict__ out,
    unsigned* ctl, short* hs, int R)
{
    const int bid = blockIdx.x;
    const int w   = threadIdx.x >> 6;
    const int l   = threadIdx.x & 63;
    const int n   = l & 15;
    const int kg  = l >> 4;
    const int Rm  = R - 1;

    if (bid < 128) {
        // ---------------- recurrence producer ----------------
        __shared__ u64 lds_h[8 * 132];     // 8 rows x 128 u64, stride 132
        const int g = bid & 7;
        const int k = bid >> 3;            // 0..15
        short* hsg = hs + (size_t)g * R * 4096;

        const int colb = k * 32 + w * 8 + (n & 3);
        const int gate = n >> 2;

        bf16x8 whF[2][16]; bf16x8 wiF[2][4]; float bregv[2];
#pragma unroll
        for (int c = 0; c < 2; ++c) {
            const int gcol = gate * 512 + colb + c * 4;
#pragma unroll
            for (int ch = 0; ch < 16; ++ch) {
                bf16x8 v;
#pragma unroll
                for (int j = 0; j < 8; ++j)
                    v[j] = f2bf(Wh[(size_t)(ch * 32 + kg * 8 + j) * G4_ + gcol]);
                whF[c][ch] = v;
            }
#pragma unroll
            for (int ch = 0; ch < 4; ++ch) {
                bf16x8 v;
#pragma unroll
                for (int j = 0; j < 8; ++j)
                    v[j] = f2bf(Wi[(size_t)(ch * 32 + kg * 8 + j) * G4_ + gcol]);
                wiF[c][ch] = v;
            }
            bregv[c] = bvec[gcol];
        }

        const bool owner = (kg < 2) && (n < 4);
        float cst[2][4], hlast[2][4];
#pragma unroll
        for (int c = 0; c < 2; ++c)
#pragma unroll
            for (int r = 0; r < 4; ++r) {
                cst[c][r] = owner ? init_c[(size_t)(g * 8 + kg * 4 + r) * H_ + colb + c * 4] : 0.f;
                hlast[c][r] = 0.f;
            }

        // obs double-buffer in registers
        f32x4 oraw[8];
        if (n < 8) {
            const float* src = obses + ((size_t)(g * 8 + n) * T_ + 0) * D_ + kg * 8;
#pragma unroll
            for (int ch = 0; ch < 4; ++ch) {
                oraw[2 * ch]     = *(const f32x4*)(src + ch * 32);
                oraw[2 * ch + 1] = *(const f32x4*)(src + ch * 32 + 4);
            }
        }

        // payload-quarter mapping: this wave loads rows 0..7, u64 cols
        // [w*32, w*32+32); lane covers row l>>3, cols w*32+(l&7)+8j (j=0..3)
        const int prow = l >> 3;
        const int pcol = w * 32 + (l & 7);

        const int CHK  = R >> 2;
        const int CHKm = CHK - 1;

        for (int t = 0; t < T_; ++t) {
            // ---- back-pressure vs qs workers (rare; uniform across waves) ----
            if ((t & CHKm) == 0) {
                const int need = t + CHK + 4 - R;
                if (need > 0) {
                    bool ok;
                    do {
                        int p = 0x7fffffff;
                        if (l < 4)
                            p = 1 + l + 4 * (int)__hip_atomic_load(ctl + QD_IDX(g, l),
                                    __ATOMIC_RELAXED, __HIP_MEMORY_SCOPE_AGENT);
                        ok = (__all(p >= need) != 0);
                    } while (!ok);
                }
            }

            // ---- x-projection from prefetched obs; prefetch next ----
            bf16x8 obsF[4];
#pragma unroll
            for (int ch = 0; ch < 4; ++ch) {
                bf16x8 v;
                if (n < 8) {
#pragma unroll
                    for (int j = 0; j < 4; ++j) {
                        v[j]     = f2bf(oraw[2 * ch][j]);
                        v[4 + j] = f2bf(oraw[2 * ch + 1][j]);
                    }
                } else {
#pragma unroll
                    for (int j = 0; j < 8; ++j) v[j] = 0;
                }
                obsF[ch] = v;
            }
            if (t + 1 < T_ && n < 8) {
                const float* src = obses + ((size_t)(g * 8 + n) * T_ + (t + 1)) * D_ + kg * 8;
#pragma unroll
                for (int ch = 0; ch < 4; ++ch) {
                    oraw[2 * ch]     = *(const f32x4*)(src + ch * 32);
                    oraw[2 * ch + 1] = *(const f32x4*)(src + ch * 32 + 4);
                }
            }

            f32x4 a0 = {bregv[0], bregv[0], bregv[0], bregv[0]};
            f32x4 a1 = {bregv[1], bregv[1], bregv[1], bregv[1]};
            f32x4 b0 = {0.f, 0.f, 0.f, 0.f}, b1 = {0.f, 0.f, 0.f, 0.f};
            a0 = MFMA(obsF[0], wiF[0][0], a0, 0, 0, 0);
            b0 = MFMA(obsF[1], wiF[0][1], b0, 0, 0, 0);
            a0 = MFMA(obsF[2], wiF[0][2], a0, 0, 0, 0);
            b0 = MFMA(obsF[3], wiF[0][3], b0, 0, 0, 0);
            a1 = MFMA(obsF[0], wiF[1][0], a1, 0, 0, 0);
            b1 = MFMA(obsF[1], wiF[1][1], b1, 0, 0, 0);
            a1 = MFMA(obsF[2], wiF[1][2], a1, 0, 0, 0);
            b1 = MFMA(obsF[3], wiF[1][3], b1, 0, 0, 0);

            // ---- wave 0 polls the 16 CU sentinels; barrier releases CU ----
            if (t > 0 && w == 0) {
                const unsigned tgt = (unsigned)t;
                bool ready;
                do {
                    unsigned v = tgt;
                    if (l < 16)
                        v = __hip_atomic_load(ctl + SEN_IDX(g, l),
                                __ATOMIC_RELAXED, __HIP_MEMORY_SCOPE_AGENT);
                    ready = (__all(v >= tgt) != 0);
                } while (!ready);
            }
            __syncthreads();

            // ---- payload quarter -> LDS (read ONCE per CU) ----
            {
                const u64* hp = (const u64*)(hsg + (size_t)(t & Rm) * 4096);
                u64 q0v = __hip_atomic_load(hp + prow * 128 + pcol,      __ATOMIC_RELAXED, __HIP_MEMORY_SCOPE_AGENT);
                u64 q1v = __hip_atomic_load(hp + prow * 128 + pcol + 8,  __ATOMIC_RELAXED, __HIP_MEMORY_SCOPE_AGENT);
                u64 q2v = __hip_atomic_load(hp + prow * 128 + pcol + 16, __ATOMIC_RELAXED, __HIP_MEMORY_SCOPE_AGENT);
                u64 q3v = __hip_atomic_load(hp + prow * 128 + pcol + 24, __ATOMIC_RELAXED, __HIP_MEMORY_SCOPE_AGENT);
                lds_h[prow * 132 + pcol]      = q0v;
                lds_h[prow * 132 + pcol + 8]  = q1v;
                lds_h[prow * 132 + pcol + 16] = q2v;
                lds_h[prow * 132 + pcol + 24] = q3v;
            }
            __syncthreads();

            // ---- recurrent MFMAs: B-frags from LDS (R10 index math) ----
            const int fbase = n * 132 + kg * 2;
#pragma unroll
            for (int ch = 0; ch < 16; ++ch) {
                union { u64 q[2]; bf16x8 v; } u;
                if (n < 8) {
                    u.q[0] = lds_h[fbase + ch * 8];
                    u.q[1] = lds_h[fbase + ch * 8 + 1];
                } else { u.q[0] = 0ull; u.q[1] = 0ull; }
                if (ch & 1) { b0 = MFMA(u.v, whF[0][ch], b0, 0, 0, 0);
                              b1 = MFMA(u.v, whF[1][ch], b1, 0, 0, 0); }
                else        { a0 = MFMA(u.v, whF[0][ch], a0, 0, 0, 0);
                              a1 = MFMA(u.v, whF[1][ch], a1, 0, 0, 0); }
            }

            // ---- gates, state update, publish raw h_{t+1} (u64 stores) ----
            const int slw = (t + 1) & Rm;
#pragma unroll
            for (int c = 0; c < 2; ++c) {
#pragma unroll
                for (int r = 0; r < 4; ++r) {
                    float x  = (c ? (a1[r] + b1[r]) : (a0[r] + b0[r]));
                    float fx = __shfl_xor(x, 4);
                    float gg = __shfl_xor(x, 8);
                    float ox = __shfl_xor(x, 12);
                    float iv = sigm(x), fv = sigm(fx), gv = tanh_(gg), ov = sigm(ox);
                    float nc = fv * cst[c][r] + iv * gv;
                    float nh = ov * tanh_(nc);
                    if (owner) { cst[c][r] = nc; hlast[c][r] = nh; }
                    unsigned mz = (unsigned)(unsigned short)f2bf(nh);
                    unsigned oz = (unsigned)__shfl_xor((int)mz, 1);
                    unsigned dw = mz | (oz << 16);
                    u64 far = (unsigned)__shfl_xor((int)dw, 2);
                    u64 qv  = (u64)dw | (far << 32);
                    if (kg < 2 && n == 0) {
                        u64* dst = (u64*)
                            (hsg + (size_t)slw * 4096 + (size_t)(kg * 4 + r) * 512 +
                             (k * 32 + w * 8 + c * 4));
                        __hip_atomic_store(dst, qv, __ATOMIC_RELAXED, __HIP_MEMORY_SCOPE_AGENT);
                    }
                }
            }
            // per-wave ack at coherence point, CU-wide rendezvous, ONE sentinel
            asm volatile("s_waitcnt vmcnt(0)" ::: "memory");
            __syncthreads();
            if (threadIdx.x == 0)
                __hip_atomic_store(ctl + SEN_IDX(g, k), (unsigned)(t + 1),
                                   __ATOMIC_RELAXED, __HIP_MEMORY_SCOPE_AGENT);
        }

        // ---- final c, h (fp32 from registers) ----
        if (owner) {
#pragma unroll
            for (int c = 0; c < 2; ++c)
#pragma unroll
                for (int r = 0; r < 4; ++r) {
                    const int brow = g * 8 + kg * 4 + r;
                    out[(size_t)brow * H_ + colb + c * 4] = cst[c][r];
                    out[(size_t)B_ * H_ + (size_t)brow * H_ + colb + c * 4] = hlast[c][r];
                }
        }
    } else {
        // ---------------- qs worker (1 CU per group) ----------------
        const int g = bid - 128;
        short* hsg = hs + (size_t)g * R * 4096;

        bf16x8 wvF[2][16]; float bvv[2];
#pragma unroll
        for (int c = 0; c < 2; ++c) {
            const int a  = c * 16 + n;
            const bool va = (a < A_);
#pragma unroll
            for (int ch = 0; ch < 16; ++ch) {
                bf16x8 v;
#pragma unroll
                for (int j = 0; j < 8; ++j)
                    v[j] = va ? f2bf(Wv[(size_t)(ch * 32 + kg * 8 + j) * A_ + a]) : (short)0;
                wvF[c][ch] = v;
            }
            bvv[c] = va ? bv[a] : 0.f;
        }

        u64 hq[32];
        if (n >= 8) {
#pragma unroll
            for (int i = 0; i < 32; ++i) hq[i] = 0ull;
        }

        unsigned cnt = 0;
        for (int s = 1 + w; s <= T_; s += 4) {
            // ---- wait for h_s: 16 CU sentinels ----
            {
                const unsigned tgt = (unsigned)s;
                bool ready;
                do {
                    unsigned v = tgt;
                    if (l < 16)
                        v = __hip_atomic_load(ctl + SEN_IDX(g, l),
                                __ATOMIC_RELAXED, __HIP_MEMORY_SCOPE_AGENT);
                    ready = (__all(v >= tgt) != 0);
                    if (!ready) __builtin_amdgcn_s_sleep(2);
                } while (!ready);
            }

            // ---- read payload once ----
            {
                const u64* hp =
                    (const u64*)(hsg + (size_t)(s & (R - 1)) * 4096) + n * 128 + kg * 2;
                if (n < 8) {
#pragma unroll
                    for (int ch = 0; ch < 16; ++ch) {
                        hq[2 * ch]     = __hip_atomic_load(hp + ch * 8,     __ATOMIC_RELAXED, __HIP_MEMORY_SCOPE_AGENT);
                        hq[2 * ch + 1] = __hip_atomic_load(hp + ch * 8 + 1, __ATOMIC_RELAXED, __HIP_MEMORY_SCOPE_AGENT);
                    }
                }
            }
            // loads complete before declaring progress (slot may be reused)
            asm volatile("s_waitcnt vmcnt(0)" ::: "memory");
            ++cnt;
            if (l == 0)
                __hip_atomic_store(ctl + QD_IDX(g, w), cnt,
                                   __ATOMIC_RELAXED, __HIP_MEMORY_SCOPE_AGENT);

            f32x4 q0 = {bvv[0], bvv[0], bvv[0], bvv[0]};
            f32x4 q1 = {bvv[1], bvv[1], bvv[1], bvv[1]};
#pragma unroll
            for (int ch = 0; ch < 16; ++ch) {
                union { u64 q[2]; bf16x8 v; } u;
                u.q[0] = hq[2 * ch]; u.q[1] = hq[2 * ch + 1];
                q0 = MFMA(u.v, wvF[0][ch], q0, 0, 0, 0);
                q1 = MFMA(u.v, wvF[1][ch], q1, 0, 0, 0);
            }

            const int tau = s - 1;
#pragma unroll
            for (int c = 0; c < 2; ++c) {
                const int a = c * 16 + n;
                if (kg < 2 && a < A_) {
                    const f32x4 q = c ? q1 : q0;
#pragma unroll
                    for (int r = 0; r < 4; ++r)
                        out[QOFF + ((size_t)(g * 8 + kg * 4 + r) * T_ + tau) * A_ + a] = q[r];
                }
            }
        }
    }
}

extern "C" void kernel_launch(void* const* d_in, const int* in_sizes, int n_in,
                              void* d_out, int out_size, void* d_ws, size_t ws_size,
                              hipStream_t stream) {
    const float* obses  = (const float*)d_in[0];
    const float* init_c = (const float*)d_in[1];
    const float* init_h = (const float*)d_in[2];
    const float* Wi     = (const float*)d_in[3];
    const float* Wh     = (const float*)d_in[4];
    const float* b      = (const float*)d_in[5];
    const float* Wv     = (const float*)d_in[6];
    const float* bv     = (const float*)d_in[7];
    float* out = (float*)d_out;

    unsigned* ctl = (unsigned*)d_ws;
    short*    hs  = (short*)((char*)d_ws + HS_OFF);

    int R = 32;
    while (R > 8 && (size_t)HS_OFF + 8ull * R * 8192ull > ws_size) R >>= 1;

    hipLaunchKernelGGL(lstm_fill,  dim3(64),  dim3(256), 0, stream, ctl);
    hipLaunchKernelGGL(lstm_init0, dim3(64),  dim3(256), 0, stream, init_h, hs, R);
    hipLaunchKernelGGL(lstm_main,  dim3(136), dim3(256), 0, stream,
                       obses, init_c, Wi, Wh, b, Wv, bv, out, ctl, hs, R);
}

// Round 12
// 14947.891 us; speedup vs baseline: 2.8028x; 1.0539x over previous
//
#include <hip/hip_runtime.h>
#include <stdint.h>
#include <stddef.h>

// LSTMQNetwork: B=64, T=4096, D=128, H=512, A=18
//
// R12 = R11's per-CU dedup + R7's data-as-flag parity protocol, merged:
//  - producers publish h' = h + s*1.5 (s = ring-generation parity sign;
//    colsum bias correction folded into gate seeds — R5/R7-proven) and do
//    NOTHING else: no vmcnt ack, no __syncthreads rendezvous, no sentinel.
//  - each consumer wave parity-polls ITS OWN 2KB payload quarter (4 u64
//    per lane, relaxed agent atomics): the detecting read IS the payload.
//    Stage into double-buffered LDS (stride 132 u64), ONE barrier, MFMA.
//  - chain/step: publish-lands -> spin catches -> LDS+bar -> MFMA+gates
//    (2 LIC legs, was 5 in R11).
//  - worker: R7's full-payload parity poll (s_sleep'd, off critical path),
//    progress counters + R7 back-pressure formula (need=t+CHK+4-R), R=32.
//  - lstm_fill stamps ring stale (0x8000); lstm_init0 seeds slot0 = h0+1.5.
//  - 4s s_memrealtime watchdog on every spin -> fail fast, never hang.

#define B_   64
#define T_   4096
#define D_   128
#define H_   512
#define G4_  2048
#define A_   18
#define QOFF (2 * B_ * H_)
#define BIAS 1.5f

typedef float f32x4  __attribute__((ext_vector_type(4)));
typedef short bf16x8 __attribute__((ext_vector_type(8)));
typedef unsigned long long u64;
#define MFMA __builtin_amdgcn_mfma_f32_16x16x32_bf16

#define QD_IDX(g,w)  (((g) * 4 + (w)) * 16)   // worker progress, 1/64B line
#define CTL_DWORDS   1024
#define HS_OFF       65536                    // ring byte offset in ws
#define TLIM         400000000ull             // ~4 s at 100 MHz
#define SMASK        0x8000800080008000ull

__device__ __forceinline__ short f2bf(float x) {
    union { float f; uint32_t u; } v; v.f = x;
    uint32_t r = (v.u + 0x7fffu + ((v.u >> 16) & 1u)) >> 16;  // RNE
    return (short)(uint16_t)r;
}
__device__ __forceinline__ float bf2f(short s) {
    union { uint32_t u; float f; } v; v.u = ((uint32_t)(uint16_t)s) << 16;
    return v.f;
}
__device__ __forceinline__ float sigm(float x) {
    return __builtin_amdgcn_rcpf(1.0f + __builtin_amdgcn_exp2f(-1.4426950408889634f * x));
}
__device__ __forceinline__ float tanh_(float x) {
    return 2.0f * __builtin_amdgcn_rcpf(1.0f + __builtin_amdgcn_exp2f(-2.8853900817779268f * x)) - 1.0f;
}

// zero ctl; stamp whole ring stale (0x8000 = -0.0 -> stale for gen 0)
__global__ void lstm_fill(unsigned* __restrict__ ctl, uint4* __restrict__ hs4,
                          int nchunks) {
    int idx = blockIdx.x * blockDim.x + threadIdx.x;
    int nt  = gridDim.x * blockDim.x;
    for (int i = idx; i < CTL_DWORDS; i += nt) ctl[i] = 0u;
    const uint4 v = {0x80008000u, 0x80008000u, 0x80008000u, 0x80008000u};
    for (int i = idx; i < nchunks; i += nt) hs4[i] = v;
}

// seed ring slot 0 with h_0 + 1.5 (generation 0 => positive sign)
__global__ void lstm_init0(const float* __restrict__ init_h,
                           short* __restrict__ hs, int R) {
    int idx = blockIdx.x * blockDim.x + threadIdx.x;
    int nt  = gridDim.x * blockDim.x;
    for (int e = idx; e < B_ * H_; e += nt) {
        int row = e >> 9, col = e & 511;
        int g = row >> 3, r8 = row & 7;
        hs[(size_t)g * R * 4096 + (size_t)r8 * 512 + col] = f2bf(init_h[e] + BIAS);
    }
}

__global__ void __launch_bounds__(256, 1) lstm_main(
    const float* __restrict__ obses, const float* __restrict__ init_c,
    const float* __restrict__ Wi,    const float* __restrict__ Wh,
    const float* __restrict__ bvec,  const float* __restrict__ Wv,
    const float* __restrict__ bv,    float* __restrict__ out,
    unsigned* ctl, short* hs, int R, int lg2R)
{
    const int bid = blockIdx.x;
    const int w   = threadIdx.x >> 6;
    const int l   = threadIdx.x & 63;
    const int n   = l & 15;
    const int kg  = l >> 4;
    const int Rm  = R - 1;
    const unsigned long long t_start = __builtin_amdgcn_s_memrealtime();
    bool tmo = false;

    if (bid < 128) {
        // ---------------- recurrence producer ----------------
        __shared__ u64 lds_h[2][8 * 132];  // double-buffered: 8 rows x 128 u64
        const int g = bid & 7;
        const int k = bid >> 3;            // 0..15
        short* hsg = hs + (size_t)g * R * 4096;

        const int colb = k * 32 + w * 8 + (n & 3);
        const int gate = n >> 2;

        bf16x8 whF[2][16]; bf16x8 wiF[2][4];
        float  whsum[2] = {0.f, 0.f}; float bregv[2];
#pragma unroll
        for (int c = 0; c < 2; ++c) {
            const int gcol = gate * 512 + colb + c * 4;
#pragma unroll
            for (int ch = 0; ch < 16; ++ch) {
                bf16x8 v;
#pragma unroll
                for (int j = 0; j < 8; ++j) {
                    short sbf = f2bf(Wh[(size_t)(ch * 32 + kg * 8 + j) * G4_ + gcol]);
                    v[j] = sbf; whsum[c] += bf2f(sbf);
                }
                whF[c][ch] = v;
            }
#pragma unroll
            for (int ch = 0; ch < 4; ++ch) {
                bf16x8 v;
#pragma unroll
                for (int j = 0; j < 8; ++j)
                    v[j] = f2bf(Wi[(size_t)(ch * 32 + kg * 8 + j) * G4_ + gcol]);
                wiF[c][ch] = v;
            }
            bregv[c] = bvec[gcol];
        }
#pragma unroll
        for (int c = 0; c < 2; ++c) {
            whsum[c] += __shfl_xor(whsum[c], 16);
            whsum[c] += __shfl_xor(whsum[c], 32);
        }

        const bool owner = (kg < 2) && (n < 4);
        float cst[2][4], hlast[2][4];
#pragma unroll
        for (int c = 0; c < 2; ++c)
#pragma unroll
            for (int r = 0; r < 4; ++r) {
                cst[c][r] = owner ? init_c[(size_t)(g * 8 + kg * 4 + r) * H_ + colb + c * 4] : 0.f;
                hlast[c][r] = 0.f;
            }

        // obs double-buffer in registers
        f32x4 oraw[8];
        if (n < 8) {
            const float* src = obses + ((size_t)(g * 8 + n) * T_ + 0) * D_ + kg * 8;
#pragma unroll
            for (int ch = 0; ch < 4; ++ch) {
                oraw[2 * ch]     = *(const f32x4*)(src + ch * 32);
                oraw[2 * ch + 1] = *(const f32x4*)(src + ch * 32 + 4);
            }
        }

        // payload-quarter mapping: wave w polls u64 cols [w*32, w*32+32),
        // lane covers row l>>3, cols w*32+(l&7)+8j, j=0..3
        const int prow = l >> 3;
        const int pcol = w * 32 + (l & 7);

        const int CHK  = R >> 2;
        const int CHKm = CHK - 1;

        for (int t = 0; t < T_ && !tmo; ++t) {
            // ---- back-pressure vs qs workers (rare) ----
            if ((t & CHKm) == 0) {
                const int need = t + CHK + 4 - R;
                if (need > 0) {
                    int spin = 0; bool ok;
                    do {
                        int p = 0x7fffffff;
                        if (l < 4)
                            p = 1 + l + 4 * (int)__hip_atomic_load(ctl + QD_IDX(g, l),
                                    __ATOMIC_RELAXED, __HIP_MEMORY_SCOPE_AGENT);
                        ok = (__all(p >= need) != 0);
                        if (!ok && ((++spin) & 63) == 0 &&
                            (__builtin_amdgcn_s_memrealtime() - t_start) > TLIM) { tmo = true; break; }
                    } while (!ok);
                    if (tmo) break;
                }
            }

            const float bh  = ((t >> lg2R) & 1) ? -BIAS : BIAS;        // sign in h_t data
            const float bh1 = (((t + 1) >> lg2R) & 1) ? -BIAS : BIAS;  // sign for h_{t+1}

            // ---- x-projection from prefetched obs; prefetch next ----
            bf16x8 obsF[4];
#pragma unroll
            for (int ch = 0; ch < 4; ++ch) {
                bf16x8 v;
                if (n < 8) {
#pragma unroll
                    for (int j = 0; j < 4; ++j) {
                        v[j]     = f2bf(oraw[2 * ch][j]);
                        v[4 + j] = f2bf(oraw[2 * ch + 1][j]);
                    }
                } else {
#pragma unroll
                    for (int j = 0; j < 8; ++j) v[j] = 0;
                }
                obsF[ch] = v;
            }
            if (t + 1 < T_ && n < 8) {
                const float* src = obses + ((size_t)(g * 8 + n) * T_ + (t + 1)) * D_ + kg * 8;
#pragma unroll
                for (int ch = 0; ch < 4; ++ch) {
                    oraw[2 * ch]     = *(const f32x4*)(src + ch * 32);
                    oraw[2 * ch + 1] = *(const f32x4*)(src + ch * 32 + 4);
                }
            }

            // split accumulator chains seeded with bias-corrected breg
            const float s0 = bregv[0] - bh * whsum[0];
            const float s1 = bregv[1] - bh * whsum[1];
            f32x4 a0 = {s0, s0, s0, s0}, b0 = {0.f, 0.f, 0.f, 0.f};
            f32x4 a1 = {s1, s1, s1, s1}, b1 = {0.f, 0.f, 0.f, 0.f};
            a0 = MFMA(obsF[0], wiF[0][0], a0, 0, 0, 0);
            b0 = MFMA(obsF[1], wiF[0][1], b0, 0, 0, 0);
            a0 = MFMA(obsF[2], wiF[0][2], a0, 0, 0, 0);
            b0 = MFMA(obsF[3], wiF[0][3], b0, 0, 0, 0);
            a1 = MFMA(obsF[0], wiF[1][0], a1, 0, 0, 0);
            b1 = MFMA(obsF[1], wiF[1][1], b1, 0, 0, 0);
            a1 = MFMA(obsF[2], wiF[1][2], a1, 0, 0, 0);
            b1 = MFMA(obsF[3], wiF[1][3], b1, 0, 0, 0);

            // ---- parity-poll OWN quarter (detecting read IS the payload) ----
            {
                const u64* hp = (const u64*)(hsg + (size_t)(t & Rm) * 4096)
                                + prow * 128 + pcol;
                const u64 e64 = (bh > 0.f) ? 0ull : SMASK;
                u64 q0v, q1v, q2v, q3v;
                int spin = 0;
                for (;;) {
                    q0v = __hip_atomic_load(hp,      __ATOMIC_RELAXED, __HIP_MEMORY_SCOPE_AGENT);
                    q1v = __hip_atomic_load(hp + 8,  __ATOMIC_RELAXED, __HIP_MEMORY_SCOPE_AGENT);
                    q2v = __hip_atomic_load(hp + 16, __ATOMIC_RELAXED, __HIP_MEMORY_SCOPE_AGENT);
                    q3v = __hip_atomic_load(hp + 24, __ATOMIC_RELAXED, __HIP_MEMORY_SCOPE_AGENT);
                    u64 bad = (q0v ^ e64) | (q1v ^ e64) | (q2v ^ e64) | (q3v ^ e64);
                    if (__all((int)((bad & SMASK) == 0ull))) break;
                    if (((++spin) & 255) == 0 &&
                        (__builtin_amdgcn_s_memrealtime() - t_start) > TLIM) { tmo = true; break; }
                }
                if (tmo) break;
                u64* dst = &lds_h[t & 1][prow * 132 + pcol];
                dst[0]  = q0v;
                dst[8]  = q1v;
                dst[16] = q2v;
                dst[24] = q3v;
            }
            __syncthreads();   // all quarters staged (dbuf -> one barrier)

            // ---- recurrent MFMAs: B-frags from LDS ----
            const u64* lb = &lds_h[t & 1][n * 132 + kg * 2];
#pragma unroll
            for (int ch = 0; ch < 16; ++ch) {
                union { u64 q[2]; bf16x8 v; } u;
                if (n < 8) { u.q[0] = lb[ch * 8]; u.q[1] = lb[ch * 8 + 1]; }
                else       { u.q[0] = 0ull; u.q[1] = 0ull; }
                if (ch & 1) { b0 = MFMA(u.v, whF[0][ch], b0, 0, 0, 0);
                              b1 = MFMA(u.v, whF[1][ch], b1, 0, 0, 0); }
                else        { a0 = MFMA(u.v, whF[0][ch], a0, 0, 0, 0);
                              a1 = MFMA(u.v, whF[1][ch], a1, 0, 0, 0); }
            }

            // ---- gates, state update, publish h'_{t+1}: fire-and-forget ----
            const int slw = (t + 1) & Rm;
#pragma unroll
            for (int c = 0; c < 2; ++c) {
#pragma unroll
                for (int r = 0; r < 4; ++r) {
                    float x  = (c ? (a1[r] + b1[r]) : (a0[r] + b0[r]));
                    float fx = __shfl_xor(x, 4);
                    float gg = __shfl_xor(x, 8);
                    float ox = __shfl_xor(x, 12);
                    float iv = sigm(x), fv = sigm(fx), gv = tanh_(gg), ov = sigm(ox);
                    float nc = fv * cst[c][r] + iv * gv;
                    float nh = ov * tanh_(nc);
                    if (owner) { cst[c][r] = nc; hlast[c][r] = nh; }
                    unsigned mz = (unsigned)(unsigned short)f2bf(nh + bh1);
                    unsigned oz = (unsigned)__shfl_xor((int)mz, 1);
                    unsigned dw = mz | (oz << 16);
                    u64 far = (unsigned)__shfl_xor((int)dw, 2);
                    u64 qv  = (u64)dw | (far << 32);
                    if (kg < 2 && n == 0) {
                        u64* dst = (u64*)
                            (hsg + (size_t)slw * 4096 + (size_t)(kg * 4 + r) * 512 +
                             (k * 32 + w * 8 + c * 4));
                        __hip_atomic_store(dst, qv, __ATOMIC_RELAXED, __HIP_MEMORY_SCOPE_AGENT);
                    }
                }
            }
            // NO ack, NO barrier, NO sentinel — parity in the data is the flag
        }

        // ---- final c, h (fp32 from registers) ----
        if (owner && !tmo) {
#pragma unroll
            for (int c = 0; c < 2; ++c)
#pragma unroll
                for (int r = 0; r < 4; ++r) {
                    const int brow = g * 8 + kg * 4 + r;
                    out[(size_t)brow * H_ + colb + c * 4] = cst[c][r];
                    out[(size_t)B_ * H_ + (size_t)brow * H_ + colb + c * 4] = hlast[c][r];
                }
        }
    } else {
        // ---------------- qs worker (1 CU per group) ----------------
        const int g = bid - 128;
        short* hsg = hs + (size_t)g * R * 4096;

        bf16x8 wvF[2][16]; float wvsum[2] = {0.f, 0.f}; float bvv[2];
#pragma unroll
        for (int c = 0; c < 2; ++c) {
            const int a  = c * 16 + n;
            const bool va = (a < A_);
#pragma unroll
            for (int ch = 0; ch < 16; ++ch) {
                bf16x8 v;
#pragma unroll
                for (int j = 0; j < 8; ++j) {
                    short sbf = va ? f2bf(Wv[(size_t)(ch * 32 + kg * 8 + j) * A_ + a]) : (short)0;
                    v[j] = sbf; wvsum[c] += bf2f(sbf);
                }
                wvF[c][ch] = v;
            }
            bvv[c] = va ? bv[a] : 0.f;
        }
#pragma unroll
        for (int c = 0; c < 2; ++c) {
            wvsum[c] += __shfl_xor(wvsum[c], 16);
            wvsum[c] += __shfl_xor(wvsum[c], 32);
        }

        u64 hq[32];
        if (n >= 8) {
#pragma unroll
            for (int i = 0; i < 32; ++i) hq[i] = 0ull;
        }

        unsigned cnt = 0;
        for (int s = 1 + w; s <= T_ && !tmo; s += 4) {
            const float bh = ((s >> lg2R) & 1) ? -BIAS : BIAS;
            const u64 e64 = (bh > 0.f) ? 0ull : SMASK;
            {
                const u64* hp = (const u64*)(hsg + (size_t)(s & Rm) * 4096)
                                + n * 128 + kg * 2;
                int spin = 0; bool fresh = true;
                do {
                    if (n < 8) {
                        u64 bad = 0;
#pragma unroll
                        for (int ch = 0; ch < 16; ++ch) {
                            hq[2 * ch]     = __hip_atomic_load(hp + ch * 8,     __ATOMIC_RELAXED, __HIP_MEMORY_SCOPE_AGENT);
                            hq[2 * ch + 1] = __hip_atomic_load(hp + ch * 8 + 1, __ATOMIC_RELAXED, __HIP_MEMORY_SCOPE_AGENT);
                        }
#pragma unroll
                        for (int i = 0; i < 32; ++i) bad |= (hq[i] ^ e64);
                        fresh = ((bad & SMASK) == 0ull);
                    }
                    if (__all(fresh)) break;
                    __builtin_amdgcn_s_sleep(2);
                    if (((++spin) & 255) == 0 &&
                        (__builtin_amdgcn_s_memrealtime() - t_start) > TLIM) { tmo = true; break; }
                } while (true);
                if (tmo) break;
            }

            // payload in regs -> progress immediately
            ++cnt;
            asm volatile("" ::: "memory");
            if (l == 0)
                __hip_atomic_store(ctl + QD_IDX(g, w), cnt,
                                   __ATOMIC_RELAXED, __HIP_MEMORY_SCOPE_AGENT);

            const float q0s = bvv[0] - bh * wvsum[0];
            const float q1s = bvv[1] - bh * wvsum[1];
            f32x4 q0 = {q0s, q0s, q0s, q0s};
            f32x4 q1 = {q1s, q1s, q1s, q1s};
#pragma unroll
            for (int ch = 0; ch < 16; ++ch) {
                union { u64 q[2]; bf16x8 v; } u;
                u.q[0] = hq[2 * ch]; u.q[1] = hq[2 * ch + 1];
                q0 = MFMA(u.v, wvF[0][ch], q0, 0, 0, 0);
                q1 = MFMA(u.v, wvF[1][ch], q1, 0, 0, 0);
            }

            const int tau = s - 1;
#pragma unroll
            for (int c = 0; c < 2; ++c) {
                const int a = c * 16 + n;
                if (kg < 2 && a < A_) {
                    const f32x4 q = c ? q1 : q0;
#pragma unroll
                    for (int r = 0; r < 4; ++r)
                        out[QOFF + ((size_t)(g * 8 + kg * 4 + r) * T_ + tau) * A_ + a] = q[r];
                }
            }
        }
    }
}

extern "C" void kernel_launch(void* const* d_in, const int* in_sizes, int n_in,
                              void* d_out, int out_size, void* d_ws, size_t ws_size,
                              hipStream_t stream) {
    const float* obses  = (const float*)d_in[0];
    const float* init_c = (const float*)d_in[1];
    const float* init_h = (const float*)d_in[2];
    const float* Wi     = (const float*)d_in[3];
    const float* Wh     = (const float*)d_in[4];
    const float* b      = (const float*)d_in[5];
    const float* Wv     = (const float*)d_in[6];
    const float* bv     = (const float*)d_in[7];
    float* out = (float*)d_out;

    unsigned* ctl = (unsigned*)d_ws;
    short*    hs  = (short*)((char*)d_ws + HS_OFF);

    int R = 32;
    while (R > 8 && (size_t)HS_OFF + 8ull * R * 8192ull > ws_size) R >>= 1;
    int lg2R = 31 - __builtin_clz((unsigned)R);

    int nchunks = R * 4096;  // 8 groups * R slots * 8192 B / 16 B

    hipLaunchKernelGGL(lstm_fill,  dim3(256), dim3(256), 0, stream, ctl, (uint4*)hs, nchunks);
    hipLaunchKernelGGL(lstm_init0, dim3(64),  dim3(256), 0, stream, init_h, hs, R);
    hipLaunchKernelGGL(lstm_main,  dim3(136), dim3(256), 0, stream,
                       obses, init_c, Wi, Wh, b, Wv, bv, out, ctl, hs, R, lg2R);
}

// Round 14
// 10563.587 us; speedup vs baseline: 3.9661x; 1.4150x over previous
//
#include <hip/hip_runtime.h>
#include <stdint.h>
#include <stddef.h>

// LSTMQNetwork: B=64, T=4096, D=128, H=512, A=18
//
// R14 = R12 (14.9ms, passed) with the producer MFMA TRANSPOSED (gates
// land in-lane), everything else byte-identical:
//  - A = weight frags (rows = gate-cols, map gc=(n&3)*512+cw+c*4+(n>>2)),
//    B = h frags — BIT-IDENTICAL to R12's LDS read (n*132+kg*2+ch*8).
//    Output C[gatecol][batch]: lane (kg,n) holds (i,f,g,o) of h-col
//    cw+c*4+kg for batch n -> 20 transcendentals/lane (was 80), no gate
//    gather shuffles, cst state 2 regs (was 8).
//  - publish: 3 pack shuffles -> lanes (kg==0,n<8) store 2 u64 (16B row
//    segment, cols cw..cw+7) via the R12-proven relaxed agent atomics.
//  - seeds: per-acc-row bias gathered once at init via shfl(s, kg*4+r),
//    two parity variants (colsum correction unchanged).
//  - fabric, parity data-as-flag protocol, ring R=32, LDS dbuf staging,
//    worker block, back-pressure: ALL unchanged from R12.
//  - XCD-local branch permanently closed (R6/R8/R9/R13: 4 failures).

#define B_   64
#define T_   4096
#define D_   128
#define H_   512
#define G4_  2048
#define A_   18
#define QOFF (2 * B_ * H_)
#define BIAS 1.5f

typedef float f32x4  __attribute__((ext_vector_type(4)));
typedef short bf16x8 __attribute__((ext_vector_type(8)));
typedef unsigned long long u64;
#define MFMA __builtin_amdgcn_mfma_f32_16x16x32_bf16

#define QD_IDX(g,w)  (((g) * 4 + (w)) * 16)   // worker progress, 1/64B line
#define CTL_DWORDS   1024
#define HS_OFF       65536                    // ring byte offset in ws
#define TLIM         400000000ull             // ~4 s at 100 MHz
#define SMASK        0x8000800080008000ull

__device__ __forceinline__ short f2bf(float x) {
    union { float f; uint32_t u; } v; v.f = x;
    uint32_t r = (v.u + 0x7fffu + ((v.u >> 16) & 1u)) >> 16;  // RNE
    return (short)(uint16_t)r;
}
__device__ __forceinline__ float bf2f(short s) {
    union { uint32_t u; float f; } v; v.u = ((uint32_t)(uint16_t)s) << 16;
    return v.f;
}
__device__ __forceinline__ float sigm(float x) {
    return __builtin_amdgcn_rcpf(1.0f + __builtin_amdgcn_exp2f(-1.4426950408889634f * x));
}
__device__ __forceinline__ float tanh_(float x) {
    return 2.0f * __builtin_amdgcn_rcpf(1.0f + __builtin_amdgcn_exp2f(-2.8853900817779268f * x)) - 1.0f;
}

// zero ctl; stamp whole ring stale (0x8000 = -0.0 -> stale for gen 0)
__global__ void lstm_fill(unsigned* __restrict__ ctl, uint4* __restrict__ hs4,
                          int nchunks) {
    int idx = blockIdx.x * blockDim.x + threadIdx.x;
    int nt  = gridDim.x * blockDim.x;
    for (int i = idx; i < CTL_DWORDS; i += nt) ctl[i] = 0u;
    const uint4 v = {0x80008000u, 0x80008000u, 0x80008000u, 0x80008000u};
    for (int i = idx; i < nchunks; i += nt) hs4[i] = v;
}

// seed ring slot 0 with h_0 + 1.5 (generation 0 => positive sign)
__global__ void lstm_init0(const float* __restrict__ init_h,
                           short* __restrict__ hs, int R) {
    int idx = blockIdx.x * blockDim.x + threadIdx.x;
    int nt  = gridDim.x * blockDim.x;
    for (int e = idx; e < B_ * H_; e += nt) {
        int row = e >> 9, col = e & 511;
        int g = row >> 3, r8 = row & 7;
        hs[(size_t)g * R * 4096 + (size_t)r8 * 512 + col] = f2bf(init_h[e] + BIAS);
    }
}

__global__ void __launch_bounds__(256, 1) lstm_main(
    const float* __restrict__ obses, const float* __restrict__ init_c,
    const float* __restrict__ Wi,    const float* __restrict__ Wh,
    const float* __restrict__ bvec,  const float* __restrict__ Wv,
    const float* __restrict__ bv,    float* __restrict__ out,
    unsigned* ctl, short* hs, int R, int lg2R)
{
    const int bid = blockIdx.x;
    const int w   = threadIdx.x >> 6;
    const int l   = threadIdx.x & 63;
    const int n   = l & 15;
    const int kg  = l >> 4;
    const int Rm  = R - 1;
    const unsigned long long t_start = __builtin_amdgcn_s_memrealtime();
    bool tmo = false;

    if (bid < 128) {
        // ---------------- recurrence producer (transposed MFMA) ----------------
        __shared__ u64 lds_h[2][8 * 132];  // double-buffered: 8 rows x 128 u64
        const int g = bid & 7;
        const int k = bid >> 3;            // 0..15
        short* hsg = hs + (size_t)g * R * 4096;

        const int cw  = k * 32 + w * 8;            // wave's h-col base
        const int gc0 = (n & 3) * 512 + cw + (n >> 2);  // A-row n -> gate col (tile0)
        const int gc1 = gc0 + 4;                        // tile1 (+4 h-cols)

        // stationary weight A-frags + colsums
        bf16x8 whA0[16], whA1[16], wiA0[4], wiA1[4];
        float ws0 = 0.f, ws1 = 0.f;
#pragma unroll
        for (int ch = 0; ch < 16; ++ch) {
            bf16x8 v0, v1;
#pragma unroll
            for (int j = 0; j < 8; ++j) {
                const size_t kr = (size_t)(ch * 32 + kg * 8 + j) * G4_;
                short s0 = f2bf(Wh[kr + gc0]); v0[j] = s0; ws0 += bf2f(s0);
                short s1 = f2bf(Wh[kr + gc1]); v1[j] = s1; ws1 += bf2f(s1);
            }
            whA0[ch] = v0; whA1[ch] = v1;
        }
#pragma unroll
        for (int ch = 0; ch < 4; ++ch) {
            bf16x8 v0, v1;
#pragma unroll
            for (int j = 0; j < 8; ++j) {
                const size_t kr = (size_t)(ch * 32 + kg * 8 + j) * G4_;
                v0[j] = f2bf(Wi[kr + gc0]);
                v1[j] = f2bf(Wi[kr + gc1]);
            }
            wiA0[ch] = v0; wiA1[ch] = v1;
        }
        // full colsum over all 512 k-rows (reduce across kg)
        ws0 += __shfl_xor(ws0, 16); ws0 += __shfl_xor(ws0, 32);
        ws1 += __shfl_xor(ws1, 16); ws1 += __shfl_xor(ws1, 32);
        const float b0v = bvec[gc0], b1v = bvec[gc1];
        const float sP0 = b0v - BIAS * ws0, sM0 = b0v + BIAS * ws0;
        const float sP1 = b1v - BIAS * ws1, sM1 = b1v + BIAS * ws1;
        // per-acc-row seeds: row a = kg*4+r -> gather from lane a (kg_src=0)
        f32x4 sdP0, sdM0, sdP1, sdM1;
#pragma unroll
        for (int r = 0; r < 4; ++r) {
            sdP0[r] = __shfl(sP0, kg * 4 + r); sdM0[r] = __shfl(sM0, kg * 4 + r);
            sdP1[r] = __shfl(sP1, kg * 4 + r); sdM1[r] = __shfl(sM1, kg * 4 + r);
        }

        // c state: lane (kg, n<8) owns batch n, cols cw+kg (t0), cw+4+kg (t1)
        float cst0 = (n < 8) ? init_c[(size_t)(g * 8 + n) * H_ + cw + kg]     : 0.f;
        float cst1 = (n < 8) ? init_c[(size_t)(g * 8 + n) * H_ + cw + 4 + kg] : 0.f;
        float hl0 = 0.f, hl1 = 0.f;

        // obs double-buffer in registers (unchanged from R12)
        f32x4 oraw[8];
        if (n < 8) {
            const float* src = obses + ((size_t)(g * 8 + n) * T_ + 0) * D_ + kg * 8;
#pragma unroll
            for (int ch = 0; ch < 4; ++ch) {
                oraw[2 * ch]     = *(const f32x4*)(src + ch * 32);
                oraw[2 * ch + 1] = *(const f32x4*)(src + ch * 32 + 4);
            }
        }

        // payload-quarter mapping (unchanged)
        const int prow = l >> 3;
        const int pcol = w * 32 + (l & 7);

        const int CHK  = R >> 2;
        const int CHKm = CHK - 1;

        for (int t = 0; t < T_ && !tmo; ++t) {
            // ---- back-pressure vs qs workers (rare) ----
            if ((t & CHKm) == 0) {
                const int need = t + CHK + 4 - R;
                if (need > 0) {
                    int spin = 0; bool ok;
                    do {
                        int p = 0x7fffffff;
                        if (l < 4)
                            p = 1 + l + 4 * (int)__hip_atomic_load(ctl + QD_IDX(g, l),
                                    __ATOMIC_RELAXED, __HIP_MEMORY_SCOPE_AGENT);
                        ok = (__all(p >= need) != 0);
                        if (!ok && ((++spin) & 63) == 0 &&
                            (__builtin_amdgcn_s_memrealtime() - t_start) > TLIM) { tmo = true; break; }
                    } while (!ok);
                    if (tmo) break;
                }
            }

            const bool  pos = (((t >> lg2R) & 1) == 0);
            const float bh1 = (((t + 1) >> lg2R) & 1) ? -BIAS : BIAS;

            // ---- x-projection from prefetched obs; prefetch next ----
            bf16x8 obsF[4];
#pragma unroll
            for (int ch = 0; ch < 4; ++ch) {
                bf16x8 v;
                if (n < 8) {
#pragma unroll
                    for (int j = 0; j < 4; ++j) {
                        v[j]     = f2bf(oraw[2 * ch][j]);
                        v[4 + j] = f2bf(oraw[2 * ch + 1][j]);
                    }
                } else {
#pragma unroll
                    for (int j = 0; j < 8; ++j) v[j] = 0;
                }
                obsF[ch] = v;
            }
            if (t + 1 < T_ && n < 8) {
                const float* src = obses + ((size_t)(g * 8 + n) * T_ + (t + 1)) * D_ + kg * 8;
#pragma unroll
                for (int ch = 0; ch < 4; ++ch) {
                    oraw[2 * ch]     = *(const f32x4*)(src + ch * 32);
                    oraw[2 * ch + 1] = *(const f32x4*)(src + ch * 32 + 4);
                }
            }

            // transposed xproj: A = Wi frags, B = obs frags; seeds per acc-row
            f32x4 aE0 = pos ? sdP0 : sdM0;
            f32x4 aE1 = pos ? sdP1 : sdM1;
            f32x4 aO0 = {0.f, 0.f, 0.f, 0.f}, aO1 = {0.f, 0.f, 0.f, 0.f};
            aE0 = MFMA(wiA0[0], obsF[0], aE0, 0, 0, 0);
            aO0 = MFMA(wiA0[1], obsF[1], aO0, 0, 0, 0);
            aE0 = MFMA(wiA0[2], obsF[2], aE0, 0, 0, 0);
            aO0 = MFMA(wiA0[3], obsF[3], aO0, 0, 0, 0);
            aE1 = MFMA(wiA1[0], obsF[0], aE1, 0, 0, 0);
            aO1 = MFMA(wiA1[1], obsF[1], aO1, 0, 0, 0);
            aE1 = MFMA(wiA1[2], obsF[2], aE1, 0, 0, 0);
            aO1 = MFMA(wiA1[3], obsF[3], aO1, 0, 0, 0);

            // ---- parity-poll OWN quarter (unchanged from R12) ----
            {
                const u64* hp = (const u64*)(hsg + (size_t)(t & Rm) * 4096)
                                + prow * 128 + pcol;
                const u64 e64 = pos ? 0ull : SMASK;
                u64 q0v, q1v, q2v, q3v;
                int spin = 0;
                for (;;) {
                    q0v = __hip_atomic_load(hp,      __ATOMIC_RELAXED, __HIP_MEMORY_SCOPE_AGENT);
                    q1v = __hip_atomic_load(hp + 8,  __ATOMIC_RELAXED, __HIP_MEMORY_SCOPE_AGENT);
                    q2v = __hip_atomic_load(hp + 16, __ATOMIC_RELAXED, __HIP_MEMORY_SCOPE_AGENT);
                    q3v = __hip_atomic_load(hp + 24, __ATOMIC_RELAXED, __HIP_MEMORY_SCOPE_AGENT);
                    u64 bad = (q0v ^ e64) | (q1v ^ e64) | (q2v ^ e64) | (q3v ^ e64);
                    if (__all((int)((bad & SMASK) == 0ull))) break;
                    if (((++spin) & 255) == 0 &&
                        (__builtin_amdgcn_s_memrealtime() - t_start) > TLIM) { tmo = true; break; }
                }
                if (tmo) break;
                u64* dst = &lds_h[t & 1][prow * 132 + pcol];
                dst[0]  = q0v;
                dst[8]  = q1v;
                dst[16] = q2v;
                dst[24] = q3v;
            }
            __syncthreads();

            // ---- recurrent MFMAs: A = Wh frags, B = h frags from LDS ----
            const u64* lb = &lds_h[t & 1][n * 132 + kg * 2];
#pragma unroll
            for (int ch = 0; ch < 16; ++ch) {
                union { u64 q[2]; bf16x8 v; } u;
                if (n < 8) { u.q[0] = lb[ch * 8]; u.q[1] = lb[ch * 8 + 1]; }
                else       { u.q[0] = 0ull; u.q[1] = 0ull; }
                if (ch & 1) { aO0 = MFMA(whA0[ch], u.v, aO0, 0, 0, 0);
                              aO1 = MFMA(whA1[ch], u.v, aO1, 0, 0, 0); }
                else        { aE0 = MFMA(whA0[ch], u.v, aE0, 0, 0, 0);
                              aE1 = MFMA(whA1[ch], u.v, aE1, 0, 0, 0); }
            }

            // ---- gates in-lane (acc regs = i,f,g,o of one h-col) ----
            f32x4 x0 = aE0 + aO0, x1 = aE1 + aO1;
            float nc0 = sigm(x0[1]) * cst0 + sigm(x0[0]) * tanh_(x0[2]);
            float nh0 = sigm(x0[3]) * tanh_(nc0);
            float nc1 = sigm(x1[1]) * cst1 + sigm(x1[0]) * tanh_(x1[2]);
            float nh1 = sigm(x1[3]) * tanh_(nc1);
            cst0 = nc0; cst1 = nc1; hl0 = nh0; hl1 = nh1;

            // ---- pack row segment (cols cw..cw+7) and publish ----
            {
                const int slw = (t + 1) & Rm;
                unsigned v = (unsigned)(unsigned short)f2bf(nh0 + bh1) |
                             ((unsigned)(unsigned short)f2bf(nh1 + bh1) << 16);
                unsigned p  = (unsigned)__shfl_xor((int)v, 16);   // kg^1
                unsigned dwA = (v & 0xffffu) | (p << 16);         // c0: kg, kg^1
                unsigned dwB = (v >> 16) | (p & 0xffff0000u);     // c1: kg, kg^1
                unsigned qA = (unsigned)__shfl_xor((int)dwA, 32); // kg^2 pair
                unsigned qB = (unsigned)__shfl_xor((int)dwB, 32);
                u64 lo = (u64)dwA | ((u64)qA << 32);  // cols cw+0..3
                u64 hi = (u64)dwB | ((u64)qB << 32);  // cols cw+4..7
                if (kg == 0 && n < 8) {
                    u64* dst = (u64*)(hsg + (size_t)slw * 4096 + (size_t)n * 512 + cw);
                    __hip_atomic_store(dst,     lo, __ATOMIC_RELAXED, __HIP_MEMORY_SCOPE_AGENT);
                    __hip_atomic_store(dst + 1, hi, __ATOMIC_RELAXED, __HIP_MEMORY_SCOPE_AGENT);
                }
            }
            // fire-and-forget — parity in the data is the flag
        }

        // ---- final c, h (fp32 from registers) ----
        if (n < 8 && !tmo) {
            const size_t brow = (size_t)(g * 8 + n);
            out[brow * H_ + cw + kg]     = cst0;
            out[brow * H_ + cw + 4 + kg] = cst1;
            out[(size_t)B_ * H_ + brow * H_ + cw + kg]     = hl0;
            out[(size_t)B_ * H_ + brow * H_ + cw + 4 + kg] = hl1;
        }
    } else {
        // ---------------- qs worker (unchanged from R12) ----------------
        const int g = bid - 128;
        short* hsg = hs + (size_t)g * R * 4096;

        bf16x8 wvF[2][16]; float wvsum[2] = {0.f, 0.f}; float bvv[2];
#pragma unroll
        for (int c = 0; c < 2; ++c) {
            const int a  = c * 16 + n;
            const bool va = (a < A_);
#pragma unroll
            for (int ch = 0; ch < 16; ++ch) {
                bf16x8 v;
#pragma unroll
                for (int j = 0; j < 8; ++j) {
                    short sbf = va ? f2bf(Wv[(size_t)(ch * 32 + kg * 8 + j) * A_ + a]) : (short)0;
                    v[j] = sbf; wvsum[c] += bf2f(sbf);
                }
                wvF[c][ch] = v;
            }
            bvv[c] = va ? bv[a] : 0.f;
        }
#pragma unroll
        for (int c = 0; c < 2; ++c) {
            wvsum[c] += __shfl_xor(wvsum[c], 16);
            wvsum[c] += __shfl_xor(wvsum[c], 32);
        }

        u64 hq[32];
        if (n >= 8) {
#pragma unroll
            for (int i = 0; i < 32; ++i) hq[i] = 0ull;
        }

        unsigned cnt = 0;
        for (int s = 1 + w; s <= T_ && !tmo; s += 4) {
            const float bh = ((s >> lg2R) & 1) ? -BIAS : BIAS;
            const u64 e64 = (bh > 0.f) ? 0ull : SMASK;
            {
                const u64* hp = (const u64*)(hsg + (size_t)(s & Rm) * 4096)
                                + n * 128 + kg * 2;
                int spin = 0; bool fresh = true;
                do {
                    if (n < 8) {
                        u64 bad = 0;
#pragma unroll
                        for (int ch = 0; ch < 16; ++ch) {
                            hq[2 * ch]     = __hip_atomic_load(hp + ch * 8,     __ATOMIC_RELAXED, __HIP_MEMORY_SCOPE_AGENT);
                            hq[2 * ch + 1] = __hip_atomic_load(hp + ch * 8 + 1, __ATOMIC_RELAXED, __HIP_MEMORY_SCOPE_AGENT);
                        }
#pragma unroll
                        for (int i = 0; i < 32; ++i) bad |= (hq[i] ^ e64);
                        fresh = ((bad & SMASK) == 0ull);
                    }
                    if (__all(fresh)) break;
                    __builtin_amdgcn_s_sleep(2);
                    if (((++spin) & 255) == 0 &&
                        (__builtin_amdgcn_s_memrealtime() - t_start) > TLIM) { tmo = true; break; }
                } while (true);
                if (tmo) break;
            }

            // payload in regs -> progress immediately
            ++cnt;
            asm volatile("" ::: "memory");
            if (l == 0)
                __hip_atomic_store(ctl + QD_IDX(g, w), cnt,
                                   __ATOMIC_RELAXED, __HIP_MEMORY_SCOPE_AGENT);

            const float q0s = bvv[0] - bh * wvsum[0];
            const float q1s = bvv[1] - bh * wvsum[1];
            f32x4 q0 = {q0s, q0s, q0s, q0s};
            f32x4 q1 = {q1s, q1s, q1s, q1s};
#pragma unroll
            for (int ch = 0; ch < 16; ++ch) {
                union { u64 q[2]; bf16x8 v; } u;
                u.q[0] = hq[2 * ch]; u.q[1] = hq[2 * ch + 1];
                q0 = MFMA(u.v, wvF[0][ch], q0, 0, 0, 0);
                q1 = MFMA(u.v, wvF[1][ch], q1, 0, 0, 0);
            }

            const int tau = s - 1;
#pragma unroll
            for (int c = 0; c < 2; ++c) {
                const int a = c * 16 + n;
                if (kg < 2 && a < A_) {
                    const f32x4 q = c ? q1 : q0;
#pragma unroll
                    for (int r = 0; r < 4; ++r)
                        out[QOFF + ((size_t)(g * 8 + kg * 4 + r) * T_ + tau) * A_ + a] = q[r];
                }
            }
        }
    }
}

extern "C" void kernel_launch(void* const* d_in, const int* in_sizes, int n_in,
                              void* d_out, int out_size, void* d_ws, size_t ws_size,
                              hipStream_t stream) {
    const float* obses  = (const float*)d_in[0];
    const float* init_c = (const float*)d_in[1];
    const float* init_h = (const float*)d_in[2];
    const float* Wi     = (const float*)d_in[3];
    const float* Wh     = (const float*)d_in[4];
    const float* b      = (const float*)d_in[5];
    const float* Wv     = (const float*)d_in[6];
    const float* bv     = (const float*)d_in[7];
    float* out = (float*)d_out;

    unsigned* ctl = (unsigned*)d_ws;
    short*    hs  = (short*)((char*)d_ws + HS_OFF);

    int R = 32;
    while (R > 8 && (size_t)HS_OFF + 8ull * R * 8192ull > ws_size) R >>= 1;
    int lg2R = 31 - __builtin_clz((unsigned)R);

    int nchunks = R * 4096;  // 8 groups * R slots * 8192 B / 16 B

    hipLaunchKernelGGL(lstm_fill,  dim3(256), dim3(256), 0, stream, ctl, (uint4*)hs, nchunks);
    hipLaunchKernelGGL(lstm_init0, dim3(64),  dim3(256), 0, stream, init_h, hs, R);
    hipLaunchKernelGGL(lstm_main,  dim3(136), dim3(256), 0, stream,
                       obses, init_c, Wi, Wh, b, Wv, bv, out, ctl, hs, R, lg2R);
}